// Round 1
// baseline (251.169 us; speedup 1.0000x reference)
//
#include <hip/hip_runtime.h>
#include <math.h>

#define HID 256
#define CIN 288      // HID + POS
#define NTOK 16384   // B*N
#define NSEQ 2048
#define NH 4
#define DHD 64
#define TWO_PI 6.2831853071795864769f

typedef __attribute__((ext_vector_type(8))) short bf16x8;
typedef __attribute__((ext_vector_type(4))) float f32x4;
typedef __attribute__((ext_vector_type(4))) unsigned short u16x4;

__device__ __forceinline__ ushort f2bf(float x) {
    unsigned u = __float_as_uint(x);
    u = (u + 0x7FFFu + ((u >> 16) & 1u)) >> 16;
    return (ushort)u;
}

__device__ __forceinline__ float fast_exp2(float x) {
    return __builtin_amdgcn_exp2f(x);   // v_exp_f32
}

// pack two fp32 -> one dword of truncated bf16 (lo=a, hi=b) via v_perm_b32
__device__ __forceinline__ unsigned pack_bf_trunc(float a, float b) {
    return __builtin_amdgcn_perm(__float_as_uint(b), __float_as_uint(a), 0x07060302u);
}

// async global->LDS, 16 B per lane: LDS dst = base + lane*16 (wave-uniform base)
__device__ __forceinline__ void gload_lds16(const ushort* g, ushort* l) {
    __builtin_amdgcn_global_load_lds(
        (const __attribute__((address_space(1))) unsigned*)g,
        (__attribute__((address_space(3))) unsigned*)l, 16, 0, 0);
}

// LDS chunk swizzle for 128B rows (8 x 16B chunks/row): uniform bank classes
__device__ __forceinline__ int sw(int row) {
    return (((row >> 3) << 1) ^ row) & 7;
}

// ---------------------------------------------------------------------------
// Kernel 1: fuse in_proj with Wq/Wk/Wv -> bf16 Weff, row-major [768][288].
// ---------------------------------------------------------------------------
__global__ void fuse_w_kernel(const float* __restrict__ inW,
                              const float* __restrict__ Wq,
                              const float* __restrict__ Wk,
                              const float* __restrict__ Wv,
                              ushort* __restrict__ Wb) {
    __shared__ float wrow[256];
    const int o = blockIdx.x;
    const int mat = blockIdx.y;
    const int t = threadIdx.x;
    if (t < 256) wrow[t] = inW[(mat * 256 + o) * 256 + t];
    __syncthreads();
    if (t >= CIN) return;
    const float* Wm = (mat == 0) ? Wq : ((mat == 1) ? Wk : Wv);
    float acc = 0.f;
#pragma unroll 4
    for (int h = 0; h < 256; ++h) acc += wrow[h] * Wm[h * CIN + t];
    Wb[(size_t)(mat * 256 + o) * CIN + t] = f2bf(acc);
}

// ---------------------------------------------------------------------------
// Kernel 2: cast out_proj_w to bf16.
// ---------------------------------------------------------------------------
__global__ void cast_wo(const float* __restrict__ Wo, ushort* __restrict__ WoB) {
    const int f = (blockIdx.x * 256 + threadIdx.x) * 4;
    const float4 a = *(const float4*)(Wo + f);
    u16x4 o = {f2bf(a.x), f2bf(a.y), f2bf(a.z), f2bf(a.w)};
    *(u16x4*)(WoB + f) = o;
}

// ---------------------------------------------------------------------------
// Kernel 3: pos2embed + 2-layer MLP (replicates reference ez/cos(px) bug).
// ---------------------------------------------------------------------------
__global__ __launch_bounds__(128) void pos_mlp_kernel(
        const float* __restrict__ icoords, const float* __restrict__ qcoords,
        const float* __restrict__ w1, const float* __restrict__ b1,
        const float* __restrict__ w2, const float* __restrict__ b2,
        ushort* __restrict__ ip, ushort* __restrict__ qp) {
    __shared__ float sw1t[96 * 32];   // [e][r] transposed
    __shared__ float sb1[32];
    __shared__ float sw2[32 * 32];    // [c][r]
    __shared__ float sb2[32];
    const int t = threadIdx.x;
    for (int i = t; i < 96 * 32; i += 128) {
        const int e = i >> 5, r = i & 31;
        sw1t[i] = w1[r * 96 + e];
    }
    for (int i = t; i < 32 * 32; i += 128) sw2[i] = w2[i];
    if (t < 32) { sb1[t] = b1[t]; sb2[t] = b2[t]; }
    __syncthreads();

    const int tok = blockIdx.x * 128 + t;
    const int which = tok >> 14;
    const int m = tok & (NTOK - 1);
    const float* cr = (which ? qcoords : icoords) + m * 4;
    const float x = cr[1] * TWO_PI;
    const float y = cr[2] * TWO_PI;
    const float z = cr[3] * TWO_PI;

    f32x4 h4[8];
#pragma unroll
    for (int r4 = 0; r4 < 8; ++r4) h4[r4] = *(const f32x4*)&sb1[r4 * 4];

    for (int jj = 0; jj < 16; ++jj) {
        const float inv = 1.0f / (1.0f + 0.0625f * (float)jj);
        const float xs = x * inv, ys = y * inv, zs = z * inv;
        const float cx = __cosf(xs);
        float vals[6];
        int idx[6];
        vals[0] = __sinf(ys);  idx[0] = 2 * jj;
        vals[1] = __cosf(ys);  idx[1] = 2 * jj + 1;
        vals[2] = __sinf(xs);  idx[2] = 32 + 2 * jj;
        vals[3] = cx;          idx[3] = 32 + 2 * jj + 1;
        vals[4] = __sinf(zs);  idx[4] = 64 + 2 * jj;
        vals[5] = cx;          idx[5] = 64 + 2 * jj + 1;   // reference bug: cos of x
#pragma unroll
        for (int u = 0; u < 6; ++u) {
            const float ev = vals[u];
            const f32x4* wr = (const f32x4*)&sw1t[idx[u] * 32];
#pragma unroll
            for (int r4 = 0; r4 < 8; ++r4) h4[r4] += ev * wr[r4];
        }
    }
#pragma unroll
    for (int r4 = 0; r4 < 8; ++r4)
#pragma unroll
        for (int j = 0; j < 4; ++j) h4[r4][j] = fmaxf(h4[r4][j], 0.f);

    ushort* dst = (which ? qp : ip) + (size_t)m * CIN + 256;
#pragma unroll
    for (int c = 0; c < 32; ++c) {
        const f32x4* w4 = (const f32x4*)&sw2[c * 32];
        f32x4 a4 = h4[0] * w4[0];
#pragma unroll
        for (int r4 = 1; r4 < 8; ++r4) a4 += h4[r4] * w4[r4];
        dst[c] = f2bf(sb2[c] + (a4[0] + a4[1]) + (a4[2] + a4[3]));
    }
}

// ---------------------------------------------------------------------------
// Kernel 4: cast X / Q_in into cols 0..255 of the bf16 concat buffers.
// ---------------------------------------------------------------------------
__global__ void cast_x_kernel(const float* __restrict__ X, const float* __restrict__ Qin,
                              ushort* __restrict__ ip, ushort* __restrict__ qp) {
    const int which = blockIdx.y;
    const size_t f = ((size_t)blockIdx.x * 256 + threadIdx.x) * 8;
    const int row = (int)(f >> 8);
    const int col = (int)(f & 255);
    const float* src = which ? Qin : X;
    ushort* dst = which ? qp : ip;
    const float4 a = *(const float4*)(src + f);
    const float4 b = *(const float4*)(src + f + 4);
    u16x4 o0 = {f2bf(a.x), f2bf(a.y), f2bf(a.z), f2bf(a.w)};
    u16x4 o1 = {f2bf(b.x), f2bf(b.y), f2bf(b.z), f2bf(b.w)};
    *(u16x4*)(dst + (size_t)row * CIN + col) = o0;
    *(u16x4*)(dst + (size_t)row * CIN + col + 4) = o1;
}

// ---------------------------------------------------------------------------
// Kernel 5: QKV projection, bf16 MFMA with LDS-staged A (global_load_lds,
// double-buffered, one barrier per k-step). grid = (128, 12); block = 4 waves.
// ---------------------------------------------------------------------------
__global__ __launch_bounds__(256) void qkv_mfma(
        const ushort* __restrict__ qp, const ushort* __restrict__ ip,
        const ushort* __restrict__ Wb, const float* __restrict__ bias,
        ushort* __restrict__ qout, ushort* __restrict__ kout, ushort* __restrict__ vout) {
    __shared__ ushort SA[2 * 4096];   // 2 x 8 KB
    const int wv = threadIdx.x >> 6, lane = threadIdx.x & 63;
    const int l16 = lane & 15, quad = lane >> 4;
    const int m0b = blockIdx.x * 128;
    const int y = blockIdx.y;
    const int mat = y >> 2;
    const int n0 = y * 64;
    const ushort* A = (mat == 0) ? qp : ip;

    size_t asrc[2];
    int adst[2];
#pragma unroll
    for (int i = 0; i < 2; ++i) {
        const int idx = wv * 128 + i * 64 + lane;
        const int row = idx >> 2, cc = idx & 3;
        asrc[i] = (size_t)(m0b + row) * CIN + cc * 8;
        adst[i] = (wv * 128 + i * 64) * 8;
    }
    int aoff[2];
#pragma unroll
    for (int s = 0; s < 2; ++s)
        aoff[s] = ((32 * wv + 16 * s + l16) * 4 + quad) * 8;

    f32x4 acc[2][4];
#pragma unroll
    for (int s = 0; s < 2; ++s)
#pragma unroll
        for (int c = 0; c < 4; ++c) acc[s][c] = (f32x4){0.f, 0.f, 0.f, 0.f};

#pragma unroll
    for (int i = 0; i < 2; ++i)
        gload_lds16(A + asrc[i], SA + adst[i]);

    for (int t = 0; t < 9; ++t) {
        __syncthreads();
        if (t + 1 < 9) {
            const int bo = ((t + 1) & 1) * 4096;
#pragma unroll
            for (int i = 0; i < 2; ++i)
                gload_lds16(A + asrc[i] + (t + 1) * 32, SA + bo + adst[i]);
        }
        const ushort* buf = SA + (t & 1) * 4096;
        const int kk = t * 32;
        bf16x8 af[2], bf[4];
#pragma unroll
        for (int s = 0; s < 2; ++s)
            af[s] = *(const bf16x8*)(buf + aoff[s]);
#pragma unroll
        for (int c = 0; c < 4; ++c)
            bf[c] = *(const bf16x8*)(Wb + (size_t)(n0 + 16 * c + l16) * CIN + kk + quad * 8);
        if (mat < 2) {
#pragma unroll
            for (int s = 0; s < 2; ++s)
#pragma unroll
                for (int c = 0; c < 4; ++c)
                    acc[s][c] = __builtin_amdgcn_mfma_f32_16x16x32_bf16(bf[c], af[s], acc[s][c], 0, 0, 0);
        } else {
#pragma unroll
            for (int s = 0; s < 2; ++s)
#pragma unroll
                for (int c = 0; c < 4; ++c)
                    acc[s][c] = __builtin_amdgcn_mfma_f32_16x16x32_bf16(af[s], bf[c], acc[s][c], 0, 0, 0);
        }
    }

    const int h = y & 3;
    const int m0 = m0b + wv * 32;
    if (mat < 2) {
        const float scale = (mat == 0) ? (0.125f * 1.44269504088896f) : 1.0f;
        ushort* out = (mat == 0) ? qout : kout;
#pragma unroll
        for (int s = 0; s < 2; ++s) {
            const int tokm = m0 + 16 * s + l16;
            const int b = tokm >> 11, nn = tokm & (NSEQ - 1);
#pragma unroll
            for (int c = 0; c < 4; ++c) {
                const f32x4 b4 = *(const f32x4*)&bias[n0 + 16 * c + quad * 4];
                u16x4 w;
#pragma unroll
                for (int r = 0; r < 4; ++r) w[r] = f2bf((acc[s][c][r] + b4[r]) * scale);
                *(u16x4*)(out + ((size_t)(b * NH + h) * NSEQ + nn) * DHD + 16 * c + quad * 4) = w;
            }
        }
    } else {
#pragma unroll
        for (int s = 0; s < 2; ++s) {
            const int tok0 = m0 + 16 * s + quad * 4;
            const int b = tok0 >> 11, nn0 = tok0 & (NSEQ - 1);
#pragma unroll
            for (int c = 0; c < 4; ++c) {
                const int d = 16 * c + l16;
                const float bv = bias[n0 + d];
                u16x4 w;
#pragma unroll
                for (int r = 0; r < 4; ++r) w[r] = f2bf(acc[s][c][r] + bv);
                *(u16x4*)(vout + ((size_t)(b * NH + h) * DHD + d) * NSEQ + nn0) = w;
            }
        }
    }
}

// ---------------------------------------------------------------------------
// Kernel 6: MFMA flash attention, fixed-max softmax, LDS-staged K/V.
// SPLIT-K version: grid (16, 32, 2) — blockIdx.z selects a 1024-key half.
// Each block computes raw (unnormalized) partial O (f32) and partial l for its
// half; fixed-max softmax => partials add linearly, normalization deferred to
// oproj. Row-sum l is accumulated on the MATRIX pipe via a ones-fragment MFMA
// (B-operand col = query, A = ones => all output regs = per-query row sum),
// removing all per-tile VALU adds and the epilogue shuffles.
// 1024 blocks -> 4 blocks/CU (LDS 32 KB allows 5) = 16 waves/CU so exp2
// (trans pipe) and MFMA phases of independent blocks overlap.
// ---------------------------------------------------------------------------
__global__ __launch_bounds__(256) void attn_kernel(
        const ushort* __restrict__ q, const ushort* __restrict__ k,
        const ushort* __restrict__ v,
        float* __restrict__ O0p, float* __restrict__ O1p,
        float* __restrict__ ls0, float* __restrict__ ls1) {
    __shared__ ushort SL[2 * 8192];   // 2 x (K 8 KB + V 8 KB)
    const int bh = blockIdx.y;
    const int half = blockIdx.z;
    const int wv = threadIdx.x >> 6;
    const int lane = threadIdx.x & 63;
    const int l16 = lane & 15, quad = lane >> 4;
    const int q0 = blockIdx.x * 128 + wv * 32;

    const ushort* qb = q + (size_t)bh * NSEQ * DHD;
    const ushort* kb = k + (size_t)bh * NSEQ * DHD;
    const ushort* vb = v + (size_t)bh * DHD * NSEQ;

    // Q B-frags for the two 16-query tiles
    bf16x8 qf[2][2];
#pragma unroll
    for (int s = 0; s < 2; ++s)
#pragma unroll
        for (int hh = 0; hh < 2; ++hh)
            qf[s][hh] = *(const bf16x8*)(qb + (size_t)(q0 + 16 * s + l16) * DHD + 32 * hh + quad * 8);

    // staging offsets: chunk idx = wv*128 + i*64 + lane over 512 chunks (64 rows x 8)
    int ksrc[2], vsrc[2], sdst[2];
#pragma unroll
    for (int i = 0; i < 2; ++i) {
        const int idx = wv * 128 + i * 64 + lane;
        const int row = idx >> 3;
        const int cg = (idx & 7) ^ sw(row);
        ksrc[i] = row * DHD + cg * 8;
        vsrc[i] = row * NSEQ + cg * 8;
        sdst[i] = (wv * 128 + i * 64) * 8;
    }

    // fragment read offsets (swizzled)
    const int krow = 8 * (l16 >> 2) + (l16 & 3);   // key-slot permutation
    int koff[2][2][2];   // [sub][m][hh]
    int voff[2][4];      // [sub][c]
#pragma unroll
    for (int sub = 0; sub < 2; ++sub) {
#pragma unroll
        for (int m = 0; m < 2; ++m) {
            const int row = sub * 32 + krow + 4 * m;
#pragma unroll
            for (int hh = 0; hh < 2; ++hh)
                koff[sub][m][hh] = (row * 8 + ((hh * 4 + quad) ^ sw(row))) * 8;
        }
#pragma unroll
        for (int c = 0; c < 4; ++c) {
            const int row = 16 * c + l16;
            voff[sub][c] = 4096 + (row * 8 + ((sub * 4 + quad) ^ sw(row))) * 8;
        }
    }

    f32x4 Oc[2][4];
#pragma unroll
    for (int s = 0; s < 2; ++s)
#pragma unroll
        for (int c = 0; c < 4; ++c) Oc[s][c] = (f32x4){0.f, 0.f, 0.f, 0.f};
    f32x4 Lc[2];
#pragma unroll
    for (int s = 0; s < 2; ++s) Lc[s] = (f32x4){0.f, 0.f, 0.f, 0.f};
    const short ob = (short)0x3F80;                         // bf16 1.0
    const bf16x8 onesf = {ob, ob, ob, ob, ob, ob, ob, ob};

    const int kbase = half * (NSEQ / 2);   // this block's 1024-key half

    // stage tile 0
#pragma unroll
    for (int i = 0; i < 2; ++i) {
        gload_lds16(kb + (size_t)kbase * DHD + ksrc[i], SL + sdst[i]);
        gload_lds16(vb + kbase + vsrc[i], SL + 4096 + sdst[i]);
    }

    for (int t = 0; t < 16; ++t) {
        __syncthreads();                      // tile t ready; buf[(t+1)&1] free
        if (t + 1 < 16) {
            const int bo = ((t + 1) & 1) * 8192;
            const int kt = kbase + (t + 1) * 64;
#pragma unroll
            for (int i = 0; i < 2; ++i) {
                gload_lds16(kb + (size_t)kt * DHD + ksrc[i], SL + bo + sdst[i]);
                gload_lds16(vb + kt + vsrc[i], SL + bo + 4096 + sdst[i]);
            }
        }
        const ushort* buf = SL + (t & 1) * 8192;

#pragma unroll
        for (int sub = 0; sub < 2; ++sub) {
            bf16x8 kf[2][2], vf[4];
#pragma unroll
            for (int m = 0; m < 2; ++m)
#pragma unroll
                for (int hh = 0; hh < 2; ++hh)
                    kf[m][hh] = *(const bf16x8*)(buf + koff[sub][m][hh]);
#pragma unroll
            for (int c = 0; c < 4; ++c)
                vf[c] = *(const bf16x8*)(buf + voff[sub][c]);

#pragma unroll
            for (int s = 0; s < 2; ++s) {
                f32x4 s0 = (f32x4){0.f, 0.f, 0.f, 0.f};
                f32x4 s1 = (f32x4){0.f, 0.f, 0.f, 0.f};
                s0 = __builtin_amdgcn_mfma_f32_16x16x32_bf16(kf[0][0], qf[s][0], s0, 0, 0, 0);
                s0 = __builtin_amdgcn_mfma_f32_16x16x32_bf16(kf[0][1], qf[s][1], s0, 0, 0, 0);
                s1 = __builtin_amdgcn_mfma_f32_16x16x32_bf16(kf[1][0], qf[s][0], s1, 0, 0, 0);
                s1 = __builtin_amdgcn_mfma_f32_16x16x32_bf16(kf[1][1], qf[s][1], s1, 0, 0, 0);
                // s includes log2(e) (folded into q): p = exp2(s)

                float p0[4], p1[4];
#pragma unroll
                for (int r = 0; r < 4; ++r) {
                    p0[r] = fast_exp2(s0[r]);
                    p1[r] = fast_exp2(s1[r]);
                }

                union { bf16x8 v8; unsigned d[4]; } P;
                P.d[0] = pack_bf_trunc(p0[0], p0[1]);
                P.d[1] = pack_bf_trunc(p0[2], p0[3]);
                P.d[2] = pack_bf_trunc(p1[0], p1[1]);
                P.d[3] = pack_bf_trunc(p1[2], p1[3]);
                // row-sum on the matrix pipe: every output reg = sum_k P[q][k]
                Lc[s] = __builtin_amdgcn_mfma_f32_16x16x32_bf16(onesf, P.v8, Lc[s], 0, 0, 0);
#pragma unroll
                for (int c = 0; c < 4; ++c)
                    Oc[s][c] = __builtin_amdgcn_mfma_f32_16x16x32_bf16(vf[c], P.v8, Oc[s][c], 0, 0, 0);
            }
        }
    }

    const int b = bh >> 2, h = bh & 3;
    float* Op = half ? O1p : O0p;
    float* lsum = half ? ls1 : ls0;
#pragma unroll
    for (int s = 0; s < 2; ++s) {
        const int query = q0 + 16 * s + l16;
        if (quad == 0) lsum[bh * NSEQ + query] = Lc[s][0];
        float* dst = Op + (size_t)(b * NSEQ + query) * HID + h * DHD;
#pragma unroll
        for (int c = 0; c < 4; ++c)
            *(f32x4*)(dst + 16 * c + quad * 4) = Oc[s][c];
    }
}

// ---------------------------------------------------------------------------
// Kernel 7: combine split-K partials + normalize (folded into A-frag load),
// then out_proj (bf16 MFMA) + bias + residual + LayerNorm.
// ---------------------------------------------------------------------------
__global__ __launch_bounds__(256) void oproj_ln_mfma(
        const float* __restrict__ O0p, const float* __restrict__ O1p,
        const float* __restrict__ ls0, const float* __restrict__ ls1,
        const float* __restrict__ Qin,
        const ushort* __restrict__ WoB, const float* __restrict__ bo,
        const float* __restrict__ g, const float* __restrict__ be,
        float* __restrict__ out) {
    __shared__ float yt[32][260];
    const int wv = threadIdx.x >> 6, lane = threadIdx.x & 63;
    const int l16 = lane & 15, quad = lane >> 4;
    const int m0 = blockIdx.x * 32;
    const int n0 = wv * 64;

    // per-(row,head) inverse softmax denominators
    float linv[2][4];
#pragma unroll
    for (int s = 0; s < 2; ++s) {
        const int tok = m0 + 16 * s + l16;
        const int b = tok >> 11, nn = tok & (NSEQ - 1);
#pragma unroll
        for (int h = 0; h < 4; ++h) {
            const int idx = (b * NH + h) * NSEQ + nn;
            linv[s][h] = 1.0f / (ls0[idx] + ls1[idx]);
        }
    }

    f32x4 acc[2][4];
#pragma unroll
    for (int s = 0; s < 2; ++s)
#pragma unroll
        for (int c = 0; c < 4; ++c) acc[s][c] = (f32x4){0.f, 0.f, 0.f, 0.f};

    for (int kk = 0; kk < HID; kk += 32) {
        const int hd = kk >> 6;
        bf16x8 af[2], bf[4];
#pragma unroll
        for (int s = 0; s < 2; ++s) {
            const size_t base = (size_t)(m0 + 16 * s + l16) * HID + kk + quad * 8;
            const f32x4 x0 = *(const f32x4*)(O0p + base);
            const f32x4 x1 = *(const f32x4*)(O0p + base + 4);
            const f32x4 y0 = *(const f32x4*)(O1p + base);
            const f32x4 y1 = *(const f32x4*)(O1p + base + 4);
            const float li = linv[s][hd];
            union { bf16x8 v8; u16x4 hx[2]; } A;
#pragma unroll
            for (int j = 0; j < 4; ++j) A.hx[0][j] = f2bf((x0[j] + y0[j]) * li);
#pragma unroll
            for (int j = 0; j < 4; ++j) A.hx[1][j] = f2bf((x1[j] + y1[j]) * li);
            af[s] = A.v8;
        }
#pragma unroll
        for (int c = 0; c < 4; ++c)
            bf[c] = *(const bf16x8*)(WoB + (size_t)(n0 + 16 * c + l16) * HID + kk + quad * 8);
#pragma unroll
        for (int s = 0; s < 2; ++s)
#pragma unroll
            for (int c = 0; c < 4; ++c)
                acc[s][c] = __builtin_amdgcn_mfma_f32_16x16x32_bf16(af[s], bf[c], acc[s][c], 0, 0, 0);
    }

#pragma unroll
    for (int s = 0; s < 2; ++s)
#pragma unroll
        for (int c = 0; c < 4; ++c) {
            const int col = n0 + 16 * c + l16;
            const float bv = bo[col];
#pragma unroll
            for (int r = 0; r < 4; ++r) {
                const int row = 16 * s + quad * 4 + r;
                yt[row][col] = acc[s][c][r] + bv + Qin[(size_t)(m0 + row) * HID + col];
            }
        }
    __syncthreads();

    float gv[4], bev[4];
#pragma unroll
    for (int u = 0; u < 4; ++u) { gv[u] = g[lane + 64 * u]; bev[u] = be[lane + 64 * u]; }

    for (int rr = 0; rr < 8; ++rr) {
        const int row = wv * 8 + rr;
        float sm = 0.f, ssq = 0.f;
        float yv[4];
#pragma unroll
        for (int u = 0; u < 4; ++u) {
            yv[u] = yt[row][lane + 64 * u];
            sm += yv[u]; ssq += yv[u] * yv[u];
        }
#pragma unroll
        for (int off = 32; off >= 1; off >>= 1) {
            sm += __shfl_xor(sm, off);
            ssq += __shfl_xor(ssq, off);
        }
        const float mu = sm * (1.f / 256.f);
        const float rs = rsqrtf(fmaxf(ssq * (1.f / 256.f) - mu * mu, 0.f) + 1e-5f);
        float* dst = out + (size_t)(m0 + row) * HID;
#pragma unroll
        for (int u = 0; u < 4; ++u)
            dst[lane + 64 * u] = (yv[u] - mu) * rs * gv[u] + bev[u];
    }
}

// ---------------------------------------------------------------------------
extern "C" void kernel_launch(void* const* d_in, const int* in_sizes, int n_in,
                              void* d_out, int out_size, void* d_ws, size_t ws_size,
                              hipStream_t stream) {
    const float* inputs       = (const float*)d_in[0];
    const float* Q_in         = (const float*)d_in[1];
    const float* input_coords = (const float*)d_in[2];
    const float* Q_in_coords  = (const float*)d_in[3];
    const float* Wq           = (const float*)d_in[4];
    const float* Wk           = (const float*)d_in[5];
    const float* Wv           = (const float*)d_in[6];
    const float* in_proj_w    = (const float*)d_in[7];
    const float* in_proj_b    = (const float*)d_in[8];
    const float* out_proj_w   = (const float*)d_in[9];
    const float* out_proj_b   = (const float*)d_in[10];
    const float* ln_g         = (const float*)d_in[11];
    const float* ln_b         = (const float*)d_in[12];
    const float* pe_w1        = (const float*)d_in[13];
    const float* pe_b1        = (const float*)d_in[14];
    const float* pe_w2        = (const float*)d_in[15];
    const float* pe_b2        = (const float*)d_in[16];

    char* ws = (char*)d_ws;
    ushort* Wb   = (ushort*)(ws);              // 768*288*2     = 442368
    ushort* WoB  = (ushort*)(ws + 442368);     // 256*256*2     = 131072
    ushort* qp   = (ushort*)(ws + 573440);     // 16384*288*2   = 9437184
    ushort* ip   = (ushort*)(ws + 10010624);   // 9437184
    ushort* qbuf = (ushort*)(ws + 19447808);   // 8388608
    ushort* kbuf = (ushort*)(ws + 27836416);   // 8388608
    ushort* vbuf = (ushort*)(ws + 36225024);   // 8388608 (transposed [bh][64][n])
    // split-K attention partials:
    // O0 ALIASES qp/ip (16.78 MB <= 18.87 MB): qp/ip are fully regenerated by
    // pos_mlp/cast_x before qkv_mfma each iteration, and attn (which writes O0)
    // runs strictly after qkv_mfma on the same stream.
    float* O0    = (float*)(ws + 573440);      // 16384*256*4 = 16777216 (aliases qp/ip)
    float* O1    = (float*)(ws + 44613632);    // 16777216
    float* ls0   = (float*)(ws + 61390848);    // 16384*4 = 65536
    float* ls1   = (float*)(ws + 61456384);    // 65536 -> end 61521920 bytes

    fuse_w_kernel<<<dim3(256, 3), 320, 0, stream>>>(in_proj_w, Wq, Wk, Wv, Wb);
    cast_wo<<<64, 256, 0, stream>>>(out_proj_w, WoB);
    pos_mlp_kernel<<<256, 128, 0, stream>>>(input_coords, Q_in_coords,
                                            pe_w1, pe_b1, pe_w2, pe_b2, ip, qp);
    cast_x_kernel<<<dim3(2048, 2), 256, 0, stream>>>(inputs, Q_in, ip, qp);
    qkv_mfma<<<dim3(128, 12), 256, 0, stream>>>(qp, ip, Wb, in_proj_b,
                                                qbuf, kbuf, vbuf);
    attn_kernel<<<dim3(16, 32, 2), 256, 0, stream>>>(qbuf, kbuf, vbuf,
                                                     O0, O1, ls0, ls1);
    oproj_ln_mfma<<<512, 256, 0, stream>>>(O0, O1, ls0, ls1, Q_in, WoB,
                                           out_proj_b, ln_g, ln_b, (float*)d_out);
}

// Round 2
// 233.058 us; speedup vs baseline: 1.0777x; 1.0777x over previous
//
#include <hip/hip_runtime.h>
#include <math.h>

#define HID 256
#define CIN 288      // HID + POS
#define NTOK 16384   // B*N
#define NSEQ 2048
#define NH 4
#define DHD 64
#define TWO_PI 6.2831853071795864769f

typedef __attribute__((ext_vector_type(8))) short bf16x8;
typedef __attribute__((ext_vector_type(4))) float f32x4;
typedef __attribute__((ext_vector_type(4))) unsigned short u16x4;

__device__ __forceinline__ ushort f2bf(float x) {
    unsigned u = __float_as_uint(x);
    u = (u + 0x7FFFu + ((u >> 16) & 1u)) >> 16;
    return (ushort)u;
}

__device__ __forceinline__ float fast_exp2(float x) {
    return __builtin_amdgcn_exp2f(x);   // v_exp_f32
}

// pack two fp32 -> one dword of truncated bf16 (lo=a, hi=b) via v_perm_b32
__device__ __forceinline__ unsigned pack_bf_trunc(float a, float b) {
    return __builtin_amdgcn_perm(__float_as_uint(b), __float_as_uint(a), 0x07060302u);
}

// async global->LDS, 16 B per lane: LDS dst = base + lane*16 (wave-uniform base)
__device__ __forceinline__ void gload_lds16(const ushort* g, ushort* l) {
    __builtin_amdgcn_global_load_lds(
        (const __attribute__((address_space(1))) unsigned*)g,
        (__attribute__((address_space(3))) unsigned*)l, 16, 0, 0);
}

// LDS chunk swizzle for 128B rows (8 x 16B chunks/row): uniform bank classes
__device__ __forceinline__ int sw(int row) {
    return (((row >> 3) << 1) ^ row) & 7;
}

// ---------------------------------------------------------------------------
// Kernel 1: fuse in_proj with Wq/Wk/Wv -> bf16 Weff, row-major [768][288].
// ---------------------------------------------------------------------------
__global__ void fuse_w_kernel(const float* __restrict__ inW,
                              const float* __restrict__ Wq,
                              const float* __restrict__ Wk,
                              const float* __restrict__ Wv,
                              ushort* __restrict__ Wb) {
    __shared__ float wrow[256];
    const int o = blockIdx.x;
    const int mat = blockIdx.y;
    const int t = threadIdx.x;
    if (t < 256) wrow[t] = inW[(mat * 256 + o) * 256 + t];
    __syncthreads();
    if (t >= CIN) return;
    const float* Wm = (mat == 0) ? Wq : ((mat == 1) ? Wk : Wv);
    float acc = 0.f;
#pragma unroll 4
    for (int h = 0; h < 256; ++h) acc += wrow[h] * Wm[h * CIN + t];
    Wb[(size_t)(mat * 256 + o) * CIN + t] = f2bf(acc);
}

// ---------------------------------------------------------------------------
// Kernel 2: cast out_proj_w to bf16.
// ---------------------------------------------------------------------------
__global__ void cast_wo(const float* __restrict__ Wo, ushort* __restrict__ WoB) {
    const int f = (blockIdx.x * 256 + threadIdx.x) * 4;
    const float4 a = *(const float4*)(Wo + f);
    u16x4 o = {f2bf(a.x), f2bf(a.y), f2bf(a.z), f2bf(a.w)};
    *(u16x4*)(WoB + f) = o;
}

// ---------------------------------------------------------------------------
// Kernel 3: pos2embed + 2-layer MLP (replicates reference ez/cos(px) bug).
// ---------------------------------------------------------------------------
__global__ __launch_bounds__(128) void pos_mlp_kernel(
        const float* __restrict__ icoords, const float* __restrict__ qcoords,
        const float* __restrict__ w1, const float* __restrict__ b1,
        const float* __restrict__ w2, const float* __restrict__ b2,
        ushort* __restrict__ ip, ushort* __restrict__ qp) {
    __shared__ float sw1t[96 * 32];   // [e][r] transposed
    __shared__ float sb1[32];
    __shared__ float sw2[32 * 32];    // [c][r]
    __shared__ float sb2[32];
    const int t = threadIdx.x;
    for (int i = t; i < 96 * 32; i += 128) {
        const int e = i >> 5, r = i & 31;
        sw1t[i] = w1[r * 96 + e];
    }
    for (int i = t; i < 32 * 32; i += 128) sw2[i] = w2[i];
    if (t < 32) { sb1[t] = b1[t]; sb2[t] = b2[t]; }
    __syncthreads();

    const int tok = blockIdx.x * 128 + t;
    const int which = tok >> 14;
    const int m = tok & (NTOK - 1);
    const float* cr = (which ? qcoords : icoords) + m * 4;
    const float x = cr[1] * TWO_PI;
    const float y = cr[2] * TWO_PI;
    const float z = cr[3] * TWO_PI;

    f32x4 h4[8];
#pragma unroll
    for (int r4 = 0; r4 < 8; ++r4) h4[r4] = *(const f32x4*)&sb1[r4 * 4];

    for (int jj = 0; jj < 16; ++jj) {
        const float inv = 1.0f / (1.0f + 0.0625f * (float)jj);
        const float xs = x * inv, ys = y * inv, zs = z * inv;
        const float cx = __cosf(xs);
        float vals[6];
        int idx[6];
        vals[0] = __sinf(ys);  idx[0] = 2 * jj;
        vals[1] = __cosf(ys);  idx[1] = 2 * jj + 1;
        vals[2] = __sinf(xs);  idx[2] = 32 + 2 * jj;
        vals[3] = cx;          idx[3] = 32 + 2 * jj + 1;
        vals[4] = __sinf(zs);  idx[4] = 64 + 2 * jj;
        vals[5] = cx;          idx[5] = 64 + 2 * jj + 1;   // reference bug: cos of x
#pragma unroll
        for (int u = 0; u < 6; ++u) {
            const float ev = vals[u];
            const f32x4* wr = (const f32x4*)&sw1t[idx[u] * 32];
#pragma unroll
            for (int r4 = 0; r4 < 8; ++r4) h4[r4] += ev * wr[r4];
        }
    }
#pragma unroll
    for (int r4 = 0; r4 < 8; ++r4)
#pragma unroll
        for (int j = 0; j < 4; ++j) h4[r4][j] = fmaxf(h4[r4][j], 0.f);

    ushort* dst = (which ? qp : ip) + (size_t)m * CIN + 256;
#pragma unroll
    for (int c = 0; c < 32; ++c) {
        const f32x4* w4 = (const f32x4*)&sw2[c * 32];
        f32x4 a4 = h4[0] * w4[0];
#pragma unroll
        for (int r4 = 1; r4 < 8; ++r4) a4 += h4[r4] * w4[r4];
        dst[c] = f2bf(sb2[c] + (a4[0] + a4[1]) + (a4[2] + a4[3]));
    }
}

// ---------------------------------------------------------------------------
// Kernel 4: cast X / Q_in into cols 0..255 of the bf16 concat buffers.
// ---------------------------------------------------------------------------
__global__ void cast_x_kernel(const float* __restrict__ X, const float* __restrict__ Qin,
                              ushort* __restrict__ ip, ushort* __restrict__ qp) {
    const int which = blockIdx.y;
    const size_t f = ((size_t)blockIdx.x * 256 + threadIdx.x) * 8;
    const int row = (int)(f >> 8);
    const int col = (int)(f & 255);
    const float* src = which ? Qin : X;
    ushort* dst = which ? qp : ip;
    const float4 a = *(const float4*)(src + f);
    const float4 b = *(const float4*)(src + f + 4);
    u16x4 o0 = {f2bf(a.x), f2bf(a.y), f2bf(a.z), f2bf(a.w)};
    u16x4 o1 = {f2bf(b.x), f2bf(b.y), f2bf(b.z), f2bf(b.w)};
    *(u16x4*)(dst + (size_t)row * CIN + col) = o0;
    *(u16x4*)(dst + (size_t)row * CIN + col + 4) = o1;
}

// ---------------------------------------------------------------------------
// Kernel 5: QKV projection, bf16 MFMA with LDS-staged A (global_load_lds,
// double-buffered, one barrier per k-step). grid = (128, 12); block = 4 waves.
// ---------------------------------------------------------------------------
__global__ __launch_bounds__(256) void qkv_mfma(
        const ushort* __restrict__ qp, const ushort* __restrict__ ip,
        const ushort* __restrict__ Wb, const float* __restrict__ bias,
        ushort* __restrict__ qout, ushort* __restrict__ kout, ushort* __restrict__ vout) {
    __shared__ ushort SA[2 * 4096];   // 2 x 8 KB
    const int wv = threadIdx.x >> 6, lane = threadIdx.x & 63;
    const int l16 = lane & 15, quad = lane >> 4;
    const int m0b = blockIdx.x * 128;
    const int y = blockIdx.y;
    const int mat = y >> 2;
    const int n0 = y * 64;
    const ushort* A = (mat == 0) ? qp : ip;

    size_t asrc[2];
    int adst[2];
#pragma unroll
    for (int i = 0; i < 2; ++i) {
        const int idx = wv * 128 + i * 64 + lane;
        const int row = idx >> 2, cc = idx & 3;
        asrc[i] = (size_t)(m0b + row) * CIN + cc * 8;
        adst[i] = (wv * 128 + i * 64) * 8;
    }
    int aoff[2];
#pragma unroll
    for (int s = 0; s < 2; ++s)
        aoff[s] = ((32 * wv + 16 * s + l16) * 4 + quad) * 8;

    f32x4 acc[2][4];
#pragma unroll
    for (int s = 0; s < 2; ++s)
#pragma unroll
        for (int c = 0; c < 4; ++c) acc[s][c] = (f32x4){0.f, 0.f, 0.f, 0.f};

#pragma unroll
    for (int i = 0; i < 2; ++i)
        gload_lds16(A + asrc[i], SA + adst[i]);

    for (int t = 0; t < 9; ++t) {
        __syncthreads();
        if (t + 1 < 9) {
            const int bo = ((t + 1) & 1) * 4096;
#pragma unroll
            for (int i = 0; i < 2; ++i)
                gload_lds16(A + asrc[i] + (t + 1) * 32, SA + bo + adst[i]);
        }
        const ushort* buf = SA + (t & 1) * 4096;
        const int kk = t * 32;
        bf16x8 af[2], bf[4];
#pragma unroll
        for (int s = 0; s < 2; ++s)
            af[s] = *(const bf16x8*)(buf + aoff[s]);
#pragma unroll
        for (int c = 0; c < 4; ++c)
            bf[c] = *(const bf16x8*)(Wb + (size_t)(n0 + 16 * c + l16) * CIN + kk + quad * 8);
        if (mat < 2) {
#pragma unroll
            for (int s = 0; s < 2; ++s)
#pragma unroll
                for (int c = 0; c < 4; ++c)
                    acc[s][c] = __builtin_amdgcn_mfma_f32_16x16x32_bf16(bf[c], af[s], acc[s][c], 0, 0, 0);
        } else {
#pragma unroll
            for (int s = 0; s < 2; ++s)
#pragma unroll
                for (int c = 0; c < 4; ++c)
                    acc[s][c] = __builtin_amdgcn_mfma_f32_16x16x32_bf16(af[s], bf[c], acc[s][c], 0, 0, 0);
        }
    }

    const int h = y & 3;
    const int m0 = m0b + wv * 32;
    if (mat < 2) {
        const float scale = (mat == 0) ? (0.125f * 1.44269504088896f) : 1.0f;
        ushort* out = (mat == 0) ? qout : kout;
#pragma unroll
        for (int s = 0; s < 2; ++s) {
            const int tokm = m0 + 16 * s + l16;
            const int b = tokm >> 11, nn = tokm & (NSEQ - 1);
#pragma unroll
            for (int c = 0; c < 4; ++c) {
                const f32x4 b4 = *(const f32x4*)&bias[n0 + 16 * c + quad * 4];
                u16x4 w;
#pragma unroll
                for (int r = 0; r < 4; ++r) w[r] = f2bf((acc[s][c][r] + b4[r]) * scale);
                *(u16x4*)(out + ((size_t)(b * NH + h) * NSEQ + nn) * DHD + 16 * c + quad * 4) = w;
            }
        }
    } else {
#pragma unroll
        for (int s = 0; s < 2; ++s) {
            const int tok0 = m0 + 16 * s + quad * 4;
            const int b = tok0 >> 11, nn0 = tok0 & (NSEQ - 1);
#pragma unroll
            for (int c = 0; c < 4; ++c) {
                const int d = 16 * c + l16;
                const float bv = bias[n0 + d];
                u16x4 w;
#pragma unroll
                for (int r = 0; r < 4; ++r) w[r] = f2bf(acc[s][c][r] + bv);
                *(u16x4*)(vout + ((size_t)(b * NH + h) * DHD + d) * NSEQ + nn0) = w;
            }
        }
    }
}

// ---------------------------------------------------------------------------
// Kernel 6: MFMA flash attention, fixed-max softmax, LDS-staged K/V.
// DEEP-PIPELINE version (T3+T4): 4 LDS buffers (64 KB), prefetch depth 3,
// counted s_waitcnt vmcnt(N) + raw s_barrier instead of __syncthreads.
// Each wave issues exactly 4 staging loads per tile (2 K + 2 V gload_lds);
// before consuming tile t it waits vmcnt(8) -> its own tile-t loads done;
// the following barrier then guarantees ALL waves' tile-t loads are done
// (every wave passed its own vmcnt(8) first). Tiles t+1..t+3 stay in flight
// ACROSS the barrier -- no drain-to-zero in the steady state, 3 tiles of
// compute cover the load latency instead of 1.
// Softmax denominator accumulated on the matrix pipe (ones-fragment MFMA):
// Lc[s][r] = full row sum for query col l16, identical across quads/regs,
// so the epilogue needs no cross-lane shuffles.
// 64 KB LDS -> 2 blocks/CU, matching the 512-block grid (16 x 32).
// ---------------------------------------------------------------------------
__global__ __launch_bounds__(256) void attn_kernel(
        const ushort* __restrict__ q, const ushort* __restrict__ k,
        const ushort* __restrict__ v, ushort* __restrict__ out) {
    __shared__ ushort SL[4 * 8192];   // 4 x (K 8 KB + V 8 KB) = 64 KB
    const int bh = blockIdx.y;
    const int wv = threadIdx.x >> 6;
    const int lane = threadIdx.x & 63;
    const int l16 = lane & 15, quad = lane >> 4;
    const int q0 = blockIdx.x * 128 + wv * 32;

    const ushort* qb = q + (size_t)bh * NSEQ * DHD;
    const ushort* kb = k + (size_t)bh * NSEQ * DHD;
    const ushort* vb = v + (size_t)bh * DHD * NSEQ;

    // Q B-frags for the two 16-query tiles
    bf16x8 qf[2][2];
#pragma unroll
    for (int s = 0; s < 2; ++s)
#pragma unroll
        for (int hh = 0; hh < 2; ++hh)
            qf[s][hh] = *(const bf16x8*)(qb + (size_t)(q0 + 16 * s + l16) * DHD + 32 * hh + quad * 8);

    // staging offsets: chunk idx = wv*128 + i*64 + lane over 512 chunks (64 rows x 8)
    int ksrc[2], vsrc[2], sdst[2];
#pragma unroll
    for (int i = 0; i < 2; ++i) {
        const int idx = wv * 128 + i * 64 + lane;
        const int row = idx >> 3;
        const int cg = (idx & 7) ^ sw(row);
        ksrc[i] = row * DHD + cg * 8;
        vsrc[i] = row * NSEQ + cg * 8;
        sdst[i] = (wv * 128 + i * 64) * 8;
    }

    // fragment read offsets (swizzled)
    const int krow = 8 * (l16 >> 2) + (l16 & 3);   // key-slot permutation
    int koff[2][2][2];   // [sub][m][hh]
    int voff[2][4];      // [sub][c]
#pragma unroll
    for (int sub = 0; sub < 2; ++sub) {
#pragma unroll
        for (int m = 0; m < 2; ++m) {
            const int row = sub * 32 + krow + 4 * m;
#pragma unroll
            for (int hh = 0; hh < 2; ++hh)
                koff[sub][m][hh] = (row * 8 + ((hh * 4 + quad) ^ sw(row))) * 8;
        }
#pragma unroll
        for (int c = 0; c < 4; ++c) {
            const int row = 16 * c + l16;
            voff[sub][c] = 4096 + (row * 8 + ((sub * 4 + quad) ^ sw(row))) * 8;
        }
    }

    f32x4 Oc[2][4];
#pragma unroll
    for (int s = 0; s < 2; ++s)
#pragma unroll
        for (int c = 0; c < 4; ++c) Oc[s][c] = (f32x4){0.f, 0.f, 0.f, 0.f};
    f32x4 Lc[2];
#pragma unroll
    for (int s = 0; s < 2; ++s) Lc[s] = (f32x4){0.f, 0.f, 0.f, 0.f};
    const short ob = (short)0x3F80;                         // bf16 1.0
    const bf16x8 onesf = {ob, ob, ob, ob, ob, ob, ob, ob};

    // prologue: prefetch tiles 0..2 into buffers 0..2 (12 loads in flight)
#pragma unroll
    for (int pt = 0; pt < 3; ++pt) {
        ushort* db = SL + pt * 8192;
#pragma unroll
        for (int i = 0; i < 2; ++i) {
            gload_lds16(kb + (size_t)pt * (64 * DHD) + ksrc[i], db + sdst[i]);
            gload_lds16(vb + pt * 64 + vsrc[i], db + 4096 + sdst[i]);
        }
    }

    for (int tb = 0; tb < 32; tb += 4) {
#pragma unroll
        for (int u = 0; u < 4; ++u) {
            const int t = tb + u;
            // wait for OWN tile-t loads (oldest 4), leave up to 8 in flight
            if (t < 30)       asm volatile("s_waitcnt vmcnt(8)" ::: "memory");
            else if (t == 30) asm volatile("s_waitcnt vmcnt(4)" ::: "memory");
            else              asm volatile("s_waitcnt vmcnt(0)" ::: "memory");
            __builtin_amdgcn_s_barrier();   // now ALL waves' tile-t loads done

            // prefetch tile t+3 into buf[(t+3)&3] (last read during tile t-1,
            // whose readers all passed the barrier above)
            if (t < 29) {
                const int pf = t + 3;
                ushort* db = SL + ((u + 3) & 3) * 8192;
                const ushort* kpt = kb + (size_t)pf * (64 * DHD);
                const ushort* vpt = vb + pf * 64;
#pragma unroll
                for (int i = 0; i < 2; ++i) {
                    gload_lds16(kpt + ksrc[i], db + sdst[i]);
                    gload_lds16(vpt + vsrc[i], db + 4096 + sdst[i]);
                }
            }
            const ushort* buf = SL + u * 8192;   // u == t & 3

#pragma unroll
            for (int sub = 0; sub < 2; ++sub) {
                bf16x8 kf[2][2], vf[4];
#pragma unroll
                for (int m = 0; m < 2; ++m)
#pragma unroll
                    for (int hh = 0; hh < 2; ++hh)
                        kf[m][hh] = *(const bf16x8*)(buf + koff[sub][m][hh]);
#pragma unroll
                for (int c = 0; c < 4; ++c)
                    vf[c] = *(const bf16x8*)(buf + voff[sub][c]);

#pragma unroll
                for (int s = 0; s < 2; ++s) {
                    f32x4 s0 = (f32x4){0.f, 0.f, 0.f, 0.f};
                    f32x4 s1 = (f32x4){0.f, 0.f, 0.f, 0.f};
                    s0 = __builtin_amdgcn_mfma_f32_16x16x32_bf16(kf[0][0], qf[s][0], s0, 0, 0, 0);
                    s0 = __builtin_amdgcn_mfma_f32_16x16x32_bf16(kf[0][1], qf[s][1], s0, 0, 0, 0);
                    s1 = __builtin_amdgcn_mfma_f32_16x16x32_bf16(kf[1][0], qf[s][0], s1, 0, 0, 0);
                    s1 = __builtin_amdgcn_mfma_f32_16x16x32_bf16(kf[1][1], qf[s][1], s1, 0, 0, 0);
                    // s includes log2(e) (folded into q): p = exp2(s)

                    float p0[4], p1[4];
#pragma unroll
                    for (int r = 0; r < 4; ++r) {
                        p0[r] = fast_exp2(s0[r]);
                        p1[r] = fast_exp2(s1[r]);
                    }

                    union { bf16x8 v8; unsigned d[4]; } P;
                    P.d[0] = pack_bf_trunc(p0[0], p0[1]);
                    P.d[1] = pack_bf_trunc(p0[2], p0[3]);
                    P.d[2] = pack_bf_trunc(p1[0], p1[1]);
                    P.d[3] = pack_bf_trunc(p1[2], p1[3]);
                    // row-sum on the matrix pipe: every output reg = sum_k P[q][k]
                    Lc[s] = __builtin_amdgcn_mfma_f32_16x16x32_bf16(onesf, P.v8, Lc[s], 0, 0, 0);
#pragma unroll
                    for (int c = 0; c < 4; ++c)
                        Oc[s][c] = __builtin_amdgcn_mfma_f32_16x16x32_bf16(vf[c], P.v8, Oc[s][c], 0, 0, 0);
                }
            }
        }
    }

    const int b = bh >> 2, h = bh & 3;
#pragma unroll
    for (int s = 0; s < 2; ++s) {
        const float linv = 1.0f / Lc[s][0];   // full denominator, quad-invariant
        ushort* dst = out + (size_t)(b * NSEQ + q0 + 16 * s + l16) * HID + h * DHD;
#pragma unroll
        for (int c = 0; c < 4; ++c) {
            u16x4 w;
#pragma unroll
            for (int r = 0; r < 4; ++r) w[r] = f2bf(Oc[s][c][r] * linv);
            *(u16x4*)(dst + 16 * c + quad * 4) = w;
        }
    }
}

// ---------------------------------------------------------------------------
// Kernel 7: out_proj (bf16 MFMA) + bias + residual + LayerNorm.
// ---------------------------------------------------------------------------
__global__ __launch_bounds__(256) void oproj_ln_mfma(
        const ushort* __restrict__ abuf, const float* __restrict__ Qin,
        const ushort* __restrict__ WoB, const float* __restrict__ bo,
        const float* __restrict__ g, const float* __restrict__ be,
        float* __restrict__ out) {
    __shared__ float yt[32][260];
    const int wv = threadIdx.x >> 6, lane = threadIdx.x & 63;
    const int l16 = lane & 15, quad = lane >> 4;
    const int m0 = blockIdx.x * 32;
    const int n0 = wv * 64;

    f32x4 acc[2][4];
#pragma unroll
    for (int s = 0; s < 2; ++s)
#pragma unroll
        for (int c = 0; c < 4; ++c) acc[s][c] = (f32x4){0.f, 0.f, 0.f, 0.f};

    for (int kk = 0; kk < HID; kk += 32) {
        bf16x8 af[2], bf[4];
#pragma unroll
        for (int s = 0; s < 2; ++s)
            af[s] = *(const bf16x8*)(abuf + (size_t)(m0 + 16 * s + l16) * HID + kk + quad * 8);
#pragma unroll
        for (int c = 0; c < 4; ++c)
            bf[c] = *(const bf16x8*)(WoB + (size_t)(n0 + 16 * c + l16) * HID + kk + quad * 8);
#pragma unroll
        for (int s = 0; s < 2; ++s)
#pragma unroll
            for (int c = 0; c < 4; ++c)
                acc[s][c] = __builtin_amdgcn_mfma_f32_16x16x32_bf16(af[s], bf[c], acc[s][c], 0, 0, 0);
    }

#pragma unroll
    for (int s = 0; s < 2; ++s)
#pragma unroll
        for (int c = 0; c < 4; ++c) {
            const int col = n0 + 16 * c + l16;
            const float bv = bo[col];
#pragma unroll
            for (int r = 0; r < 4; ++r) {
                const int row = 16 * s + quad * 4 + r;
                yt[row][col] = acc[s][c][r] + bv + Qin[(size_t)(m0 + row) * HID + col];
            }
        }
    __syncthreads();

    float gv[4], bev[4];
#pragma unroll
    for (int u = 0; u < 4; ++u) { gv[u] = g[lane + 64 * u]; bev[u] = be[lane + 64 * u]; }

    for (int rr = 0; rr < 8; ++rr) {
        const int row = wv * 8 + rr;
        float sm = 0.f, ssq = 0.f;
        float yv[4];
#pragma unroll
        for (int u = 0; u < 4; ++u) {
            yv[u] = yt[row][lane + 64 * u];
            sm += yv[u]; ssq += yv[u] * yv[u];
        }
#pragma unroll
        for (int off = 32; off >= 1; off >>= 1) {
            sm += __shfl_xor(sm, off);
            ssq += __shfl_xor(ssq, off);
        }
        const float mu = sm * (1.f / 256.f);
        const float rs = rsqrtf(fmaxf(ssq * (1.f / 256.f) - mu * mu, 0.f) + 1e-5f);
        float* dst = out + (size_t)(m0 + row) * HID;
#pragma unroll
        for (int u = 0; u < 4; ++u)
            dst[lane + 64 * u] = (yv[u] - mu) * rs * gv[u] + bev[u];
    }
}

// ---------------------------------------------------------------------------
extern "C" void kernel_launch(void* const* d_in, const int* in_sizes, int n_in,
                              void* d_out, int out_size, void* d_ws, size_t ws_size,
                              hipStream_t stream) {
    const float* inputs       = (const float*)d_in[0];
    const float* Q_in         = (const float*)d_in[1];
    const float* input_coords = (const float*)d_in[2];
    const float* Q_in_coords  = (const float*)d_in[3];
    const float* Wq           = (const float*)d_in[4];
    const float* Wk           = (const float*)d_in[5];
    const float* Wv           = (const float*)d_in[6];
    const float* in_proj_w    = (const float*)d_in[7];
    const float* in_proj_b    = (const float*)d_in[8];
    const float* out_proj_w   = (const float*)d_in[9];
    const float* out_proj_b   = (const float*)d_in[10];
    const float* ln_g         = (const float*)d_in[11];
    const float* ln_b         = (const float*)d_in[12];
    const float* pe_w1        = (const float*)d_in[13];
    const float* pe_b1        = (const float*)d_in[14];
    const float* pe_w2        = (const float*)d_in[15];
    const float* pe_b2        = (const float*)d_in[16];

    char* ws = (char*)d_ws;
    ushort* Wb   = (ushort*)(ws);              // 768*288*2     = 442368
    ushort* WoB  = (ushort*)(ws + 442368);     // 256*256*2     = 131072
    ushort* qp   = (ushort*)(ws + 573440);     // 16384*288*2   = 9437184
    ushort* ip   = (ushort*)(ws + 10010624);   // 9437184
    ushort* qbuf = (ushort*)(ws + 19447808);   // 8388608
    ushort* kbuf = (ushort*)(ws + 27836416);   // 8388608
    ushort* vbuf = (ushort*)(ws + 36225024);   // 8388608 (transposed [bh][64][n])
    ushort* abuf = (ushort*)(ws + 44613632);   // 8388608 -> end 53002240 bytes

    fuse_w_kernel<<<dim3(256, 3), 320, 0, stream>>>(in_proj_w, Wq, Wk, Wv, Wb);
    cast_wo<<<64, 256, 0, stream>>>(out_proj_w, WoB);
    pos_mlp_kernel<<<256, 128, 0, stream>>>(input_coords, Q_in_coords,
                                            pe_w1, pe_b1, pe_w2, pe_b2, ip, qp);
    cast_x_kernel<<<dim3(2048, 2), 256, 0, stream>>>(inputs, Q_in, ip, qp);
    qkv_mfma<<<dim3(128, 12), 256, 0, stream>>>(qp, ip, Wb, in_proj_b,
                                                qbuf, kbuf, vbuf);
    attn_kernel<<<dim3(16, 32), 256, 0, stream>>>(qbuf, kbuf, vbuf, abuf);
    oproj_ln_mfma<<<512, 256, 0, stream>>>(abuf, Q_in, WoB, out_proj_b,
                                           ln_g, ln_b, (float*)d_out);
}

// Round 3
// 230.512 us; speedup vs baseline: 1.0896x; 1.0110x over previous
//
#include <hip/hip_runtime.h>
#include <math.h>

#define HID 256
#define CIN 288      // HID + POS
#define NTOK 16384   // B*N
#define NSEQ 2048
#define NH 4
#define DHD 64
#define TWO_PI 6.2831853071795864769f

typedef __attribute__((ext_vector_type(8))) short bf16x8;
typedef __attribute__((ext_vector_type(4))) float f32x4;
typedef __attribute__((ext_vector_type(4))) unsigned short u16x4;

__device__ __forceinline__ ushort f2bf(float x) {
    unsigned u = __float_as_uint(x);
    u = (u + 0x7FFFu + ((u >> 16) & 1u)) >> 16;
    return (ushort)u;
}

__device__ __forceinline__ float fast_exp2(float x) {
    return __builtin_amdgcn_exp2f(x);   // v_exp_f32
}

// pack two fp32 -> one dword of truncated bf16 (lo=a, hi=b) via v_perm_b32
__device__ __forceinline__ unsigned pack_bf_trunc(float a, float b) {
    return __builtin_amdgcn_perm(__float_as_uint(b), __float_as_uint(a), 0x07060302u);
}

// async global->LDS, 16 B per lane: LDS dst = base + lane*16 (wave-uniform base)
__device__ __forceinline__ void gload_lds16(const ushort* g, ushort* l) {
    __builtin_amdgcn_global_load_lds(
        (const __attribute__((address_space(1))) unsigned*)g,
        (__attribute__((address_space(3))) unsigned*)l, 16, 0, 0);
}

// LDS chunk swizzle for 128B rows (8 x 16B chunks/row): uniform bank classes
__device__ __forceinline__ int sw(int row) {
    return (((row >> 3) << 1) ^ row) & 7;
}

// chunk swizzle for 64B rows (4 x 16B chunks/row)
__device__ __forceinline__ int swv(int row) {
    return ((row & 3) ^ ((row >> 2) & 3));
}

// ---------------------------------------------------------------------------
// Kernel 1: fuse in_proj with Wq/Wk/Wv -> bf16 Weff, row-major [768][288].
// ---------------------------------------------------------------------------
__global__ void fuse_w_kernel(const float* __restrict__ inW,
                              const float* __restrict__ Wq,
                              const float* __restrict__ Wk,
                              const float* __restrict__ Wv,
                              ushort* __restrict__ Wb) {
    __shared__ float wrow[256];
    const int o = blockIdx.x;
    const int mat = blockIdx.y;
    const int t = threadIdx.x;
    if (t < 256) wrow[t] = inW[(mat * 256 + o) * 256 + t];
    __syncthreads();
    if (t >= CIN) return;
    const float* Wm = (mat == 0) ? Wq : ((mat == 1) ? Wk : Wv);
    float acc = 0.f;
#pragma unroll 4
    for (int h = 0; h < 256; ++h) acc += wrow[h] * Wm[h * CIN + t];
    Wb[(size_t)(mat * 256 + o) * CIN + t] = f2bf(acc);
}

// ---------------------------------------------------------------------------
// Kernel 2: cast out_proj_w to bf16.
// ---------------------------------------------------------------------------
__global__ void cast_wo(const float* __restrict__ Wo, ushort* __restrict__ WoB) {
    const int f = (blockIdx.x * 256 + threadIdx.x) * 4;
    const float4 a = *(const float4*)(Wo + f);
    u16x4 o = {f2bf(a.x), f2bf(a.y), f2bf(a.z), f2bf(a.w)};
    *(u16x4*)(WoB + f) = o;
}

// ---------------------------------------------------------------------------
// Kernel 3: pos2embed + 2-layer MLP (replicates reference ez/cos(px) bug).
// ---------------------------------------------------------------------------
__global__ __launch_bounds__(128) void pos_mlp_kernel(
        const float* __restrict__ icoords, const float* __restrict__ qcoords,
        const float* __restrict__ w1, const float* __restrict__ b1,
        const float* __restrict__ w2, const float* __restrict__ b2,
        ushort* __restrict__ ip, ushort* __restrict__ qp) {
    __shared__ float sw1t[96 * 32];   // [e][r] transposed
    __shared__ float sb1[32];
    __shared__ float sw2[32 * 32];    // [c][r]
    __shared__ float sb2[32];
    const int t = threadIdx.x;
    for (int i = t; i < 96 * 32; i += 128) {
        const int e = i >> 5, r = i & 31;
        sw1t[i] = w1[r * 96 + e];
    }
    for (int i = t; i < 32 * 32; i += 128) sw2[i] = w2[i];
    if (t < 32) { sb1[t] = b1[t]; sb2[t] = b2[t]; }
    __syncthreads();

    const int tok = blockIdx.x * 128 + t;
    const int which = tok >> 14;
    const int m = tok & (NTOK - 1);
    const float* cr = (which ? qcoords : icoords) + m * 4;
    const float x = cr[1] * TWO_PI;
    const float y = cr[2] * TWO_PI;
    const float z = cr[3] * TWO_PI;

    f32x4 h4[8];
#pragma unroll
    for (int r4 = 0; r4 < 8; ++r4) h4[r4] = *(const f32x4*)&sb1[r4 * 4];

    for (int jj = 0; jj < 16; ++jj) {
        const float inv = 1.0f / (1.0f + 0.0625f * (float)jj);
        const float xs = x * inv, ys = y * inv, zs = z * inv;
        const float cx = __cosf(xs);
        float vals[6];
        int idx[6];
        vals[0] = __sinf(ys);  idx[0] = 2 * jj;
        vals[1] = __cosf(ys);  idx[1] = 2 * jj + 1;
        vals[2] = __sinf(xs);  idx[2] = 32 + 2 * jj;
        vals[3] = cx;          idx[3] = 32 + 2 * jj + 1;
        vals[4] = __sinf(zs);  idx[4] = 64 + 2 * jj;
        vals[5] = cx;          idx[5] = 64 + 2 * jj + 1;   // reference bug: cos of x
#pragma unroll
        for (int u = 0; u < 6; ++u) {
            const float ev = vals[u];
            const f32x4* wr = (const f32x4*)&sw1t[idx[u] * 32];
#pragma unroll
            for (int r4 = 0; r4 < 8; ++r4) h4[r4] += ev * wr[r4];
        }
    }
#pragma unroll
    for (int r4 = 0; r4 < 8; ++r4)
#pragma unroll
        for (int j = 0; j < 4; ++j) h4[r4][j] = fmaxf(h4[r4][j], 0.f);

    ushort* dst = (which ? qp : ip) + (size_t)m * CIN + 256;
#pragma unroll
    for (int c = 0; c < 32; ++c) {
        const f32x4* w4 = (const f32x4*)&sw2[c * 32];
        f32x4 a4 = h4[0] * w4[0];
#pragma unroll
        for (int r4 = 1; r4 < 8; ++r4) a4 += h4[r4] * w4[r4];
        dst[c] = f2bf(sb2[c] + (a4[0] + a4[1]) + (a4[2] + a4[3]));
    }
}

// ---------------------------------------------------------------------------
// Kernel 4: cast X / Q_in into cols 0..255 of the bf16 concat buffers.
// ---------------------------------------------------------------------------
__global__ void cast_x_kernel(const float* __restrict__ X, const float* __restrict__ Qin,
                              ushort* __restrict__ ip, ushort* __restrict__ qp) {
    const int which = blockIdx.y;
    const size_t f = ((size_t)blockIdx.x * 256 + threadIdx.x) * 8;
    const int row = (int)(f >> 8);
    const int col = (int)(f & 255);
    const float* src = which ? Qin : X;
    ushort* dst = which ? qp : ip;
    const float4 a = *(const float4*)(src + f);
    const float4 b = *(const float4*)(src + f + 4);
    u16x4 o0 = {f2bf(a.x), f2bf(a.y), f2bf(a.z), f2bf(a.w)};
    u16x4 o1 = {f2bf(b.x), f2bf(b.y), f2bf(b.z), f2bf(b.w)};
    *(u16x4*)(dst + (size_t)row * CIN + col) = o0;
    *(u16x4*)(dst + (size_t)row * CIN + col + 4) = o1;
}

// ---------------------------------------------------------------------------
// Kernel 5: QKV projection, bf16 MFMA with LDS-staged A (global_load_lds,
// double-buffered, one barrier per k-step). grid = (128, 12); block = 4 waves.
// ---------------------------------------------------------------------------
__global__ __launch_bounds__(256) void qkv_mfma(
        const ushort* __restrict__ qp, const ushort* __restrict__ ip,
        const ushort* __restrict__ Wb, const float* __restrict__ bias,
        ushort* __restrict__ qout, ushort* __restrict__ kout, ushort* __restrict__ vout) {
    __shared__ ushort SA[2 * 4096];   // 2 x 8 KB
    const int wv = threadIdx.x >> 6, lane = threadIdx.x & 63;
    const int l16 = lane & 15, quad = lane >> 4;
    const int m0b = blockIdx.x * 128;
    const int y = blockIdx.y;
    const int mat = y >> 2;
    const int n0 = y * 64;
    const ushort* A = (mat == 0) ? qp : ip;

    size_t asrc[2];
    int adst[2];
#pragma unroll
    for (int i = 0; i < 2; ++i) {
        const int idx = wv * 128 + i * 64 + lane;
        const int row = idx >> 2, cc = idx & 3;
        asrc[i] = (size_t)(m0b + row) * CIN + cc * 8;
        adst[i] = (wv * 128 + i * 64) * 8;
    }
    int aoff[2];
#pragma unroll
    for (int s = 0; s < 2; ++s)
        aoff[s] = ((32 * wv + 16 * s + l16) * 4 + quad) * 8;

    f32x4 acc[2][4];
#pragma unroll
    for (int s = 0; s < 2; ++s)
#pragma unroll
        for (int c = 0; c < 4; ++c) acc[s][c] = (f32x4){0.f, 0.f, 0.f, 0.f};

#pragma unroll
    for (int i = 0; i < 2; ++i)
        gload_lds16(A + asrc[i], SA + adst[i]);

    for (int t = 0; t < 9; ++t) {
        __syncthreads();
        if (t + 1 < 9) {
            const int bo = ((t + 1) & 1) * 4096;
#pragma unroll
            for (int i = 0; i < 2; ++i)
                gload_lds16(A + asrc[i] + (t + 1) * 32, SA + bo + adst[i]);
        }
        const ushort* buf = SA + (t & 1) * 4096;
        const int kk = t * 32;
        bf16x8 af[2], bf[4];
#pragma unroll
        for (int s = 0; s < 2; ++s)
            af[s] = *(const bf16x8*)(buf + aoff[s]);
#pragma unroll
        for (int c = 0; c < 4; ++c)
            bf[c] = *(const bf16x8*)(Wb + (size_t)(n0 + 16 * c + l16) * CIN + kk + quad * 8);
        if (mat < 2) {
#pragma unroll
            for (int s = 0; s < 2; ++s)
#pragma unroll
                for (int c = 0; c < 4; ++c)
                    acc[s][c] = __builtin_amdgcn_mfma_f32_16x16x32_bf16(bf[c], af[s], acc[s][c], 0, 0, 0);
        } else {
#pragma unroll
            for (int s = 0; s < 2; ++s)
#pragma unroll
                for (int c = 0; c < 4; ++c)
                    acc[s][c] = __builtin_amdgcn_mfma_f32_16x16x32_bf16(af[s], bf[c], acc[s][c], 0, 0, 0);
        }
    }

    const int h = y & 3;
    const int m0 = m0b + wv * 32;
    if (mat < 2) {
        const float scale = (mat == 0) ? (0.125f * 1.44269504088896f) : 1.0f;
        ushort* out = (mat == 0) ? qout : kout;
#pragma unroll
        for (int s = 0; s < 2; ++s) {
            const int tokm = m0 + 16 * s + l16;
            const int b = tokm >> 11, nn = tokm & (NSEQ - 1);
#pragma unroll
            for (int c = 0; c < 4; ++c) {
                const f32x4 b4 = *(const f32x4*)&bias[n0 + 16 * c + quad * 4];
                u16x4 w;
#pragma unroll
                for (int r = 0; r < 4; ++r) w[r] = f2bf((acc[s][c][r] + b4[r]) * scale);
                *(u16x4*)(out + ((size_t)(b * NH + h) * NSEQ + nn) * DHD + 16 * c + quad * 4) = w;
            }
        }
    } else {
#pragma unroll
        for (int s = 0; s < 2; ++s) {
            const int tok0 = m0 + 16 * s + quad * 4;
            const int b = tok0 >> 11, nn0 = tok0 & (NSEQ - 1);
#pragma unroll
            for (int c = 0; c < 4; ++c) {
                const int d = 16 * c + l16;
                const float bv = bias[n0 + d];
                u16x4 w;
#pragma unroll
                for (int r = 0; r < 4; ++r) w[r] = f2bf(acc[s][c][r] + bv);
                *(u16x4*)(vout + ((size_t)(b * NH + h) * DHD + d) * NSEQ + nn0) = w;
            }
        }
    }
}

// ---------------------------------------------------------------------------
// Kernel 6: MFMA flash attention, fixed-max softmax.
// IN-BLOCK SPLIT-K, 8 waves (512 thr): waves 0-3 = keys 0..1023, waves 4-7 =
// keys 1024..2047, SAME 128 queries (32 q/wave -> LDS-read reuse preserved).
// Total waves 2048 -> 4096 = 4 waves/SIMD (was 2): fills the dependency-stall
// gap seen as MfmaUtil 33 / VALUBusy 42 / 25% idle at 2 streams/SIMD.
// 32-key tiles; per group 3 buffers x (K 4KB + V 4KB) = 24KB; 2 groups = 48KB
// -> 2 blocks/CU (96KB). Counted vmcnt pipeline (depth 2, 2 loads/wave/tile,
// wait vmcnt(2), never 0 until tail). Halves combined in LDS (no extra HBM
// traffic, unlike global split-K). Row-sum via 2 epilogue shuffles.
// ---------------------------------------------------------------------------
__global__ __launch_bounds__(512, 4) void attn_kernel(
        const ushort* __restrict__ q, const ushort* __restrict__ k,
        const ushort* __restrict__ v, ushort* __restrict__ out) {
    __shared__ ushort SL[24576];   // 48 KB
    const int bh = blockIdx.y;
    const int wv = threadIdx.x >> 6;     // 0..7
    const int grp = wv >> 2;             // key half
    const int wq = wv & 3;               // q sub-block within group
    const int lane = threadIdx.x & 63;
    const int l16 = lane & 15, quad = lane >> 4;
    const int q0 = blockIdx.x * 128 + wq * 32;

    const ushort* qb = q + (size_t)bh * NSEQ * DHD;
    const ushort* kb = k + (size_t)bh * NSEQ * DHD + (size_t)(grp * 1024) * DHD;
    const ushort* vb = v + (size_t)bh * DHD * NSEQ + grp * 1024;
    ushort* SG = SL + grp * 12288;       // per-group staging base (ushorts)

    // Q B-frags for the two 16-query tiles
    bf16x8 qf[2][2];
#pragma unroll
    for (int s = 0; s < 2; ++s)
#pragma unroll
        for (int hh = 0; hh < 2; ++hh)
            qf[s][hh] = *(const bf16x8*)(qb + (size_t)(q0 + 16 * s + l16) * DHD + 32 * hh + quad * 8);

    // staging: per tile, wave wq loads 1 K-chunk-block + 1 V-chunk-block (1KB each)
    // K tile: 32 rows x 128B (8 chunks/row); wave covers rows 8wq..8wq+7
    const int krow_s = 8 * wq + (lane >> 3);
    const int kcg = (lane & 7) ^ sw(krow_s);
    const size_t ksrc = (size_t)krow_s * DHD + kcg * 8;
    const int kdst = wq * 512;           // ushorts; HW adds lane*16B
    // V tile (V^T): 64 rows(d) x 64B (4 chunks/row); wave covers d 16wq..16wq+15
    const int vrow_s = 16 * wq + (lane >> 2);
    const int vcg = (lane & 3) ^ swv(vrow_s);
    const size_t vsrc = (size_t)vrow_s * NSEQ + vcg * 8;
    const int vdst = wq * 512;

    // fragment read offsets (swizzled; ushort units, relative to buffer base)
    const int krow = 8 * (l16 >> 2) + (l16 & 3);   // key-slot permutation
    int koff[2][2];   // [m][hh]
    int voff[4];      // [c]
#pragma unroll
    for (int m = 0; m < 2; ++m) {
        const int row = krow + 4 * m;
#pragma unroll
        for (int hh = 0; hh < 2; ++hh)
            koff[m][hh] = row * 64 + (((hh * 4 + quad) ^ sw(row))) * 8;
    }
#pragma unroll
    for (int c = 0; c < 4; ++c) {
        const int d = 16 * c + l16;
        voff[c] = 2048 + d * 32 + ((quad ^ swv(d))) * 8;
    }

    f32x4 Oc[2][4];
#pragma unroll
    for (int s = 0; s < 2; ++s)
#pragma unroll
        for (int c = 0; c < 4; ++c) Oc[s][c] = (f32x4){0.f, 0.f, 0.f, 0.f};
    float lr[2] = {0.f, 0.f};

    // prologue: prefetch tiles 0,1 (4 loads in flight)
#pragma unroll
    for (int pt = 0; pt < 2; ++pt) {
        ushort* db = SG + pt * 4096;
        gload_lds16(kb + (size_t)(pt * 32) * DHD + ksrc, db + kdst);
        gload_lds16(vb + pt * 32 + vsrc, db + 2048 + vdst);
    }

    int co = 0, po = 8192;   // consumer / prefetch buffer offsets (ushorts)
    for (int t = 0; t < 32; ++t) {
        // retire OWN tile-t loads (leave tile t+1 in flight); barrier => all waves'
        if (t < 31) asm volatile("s_waitcnt vmcnt(2)" ::: "memory");
        else        asm volatile("s_waitcnt vmcnt(0)" ::: "memory");
        __builtin_amdgcn_s_barrier();

        if (t < 30) {   // prefetch tile t+2 into buf freed at t-1
            ushort* db = SG + po;
            gload_lds16(kb + (size_t)((t + 2) * 32) * DHD + ksrc, db + kdst);
            gload_lds16(vb + (t + 2) * 32 + vsrc, db + 2048 + vdst);
            po = (po == 8192) ? 0 : po + 4096;
        }
        const ushort* buf = SG + co;
        co = (co == 8192) ? 0 : co + 4096;

        bf16x8 kf[2][2], vf[4];
#pragma unroll
        for (int m = 0; m < 2; ++m)
#pragma unroll
            for (int hh = 0; hh < 2; ++hh)
                kf[m][hh] = *(const bf16x8*)(buf + koff[m][hh]);
#pragma unroll
        for (int c = 0; c < 4; ++c)
            vf[c] = *(const bf16x8*)(buf + voff[c]);

#pragma unroll
        for (int s = 0; s < 2; ++s) {
            f32x4 s0 = (f32x4){0.f, 0.f, 0.f, 0.f};
            f32x4 s1 = (f32x4){0.f, 0.f, 0.f, 0.f};
            s0 = __builtin_amdgcn_mfma_f32_16x16x32_bf16(kf[0][0], qf[s][0], s0, 0, 0, 0);
            s0 = __builtin_amdgcn_mfma_f32_16x16x32_bf16(kf[0][1], qf[s][1], s0, 0, 0, 0);
            s1 = __builtin_amdgcn_mfma_f32_16x16x32_bf16(kf[1][0], qf[s][0], s1, 0, 0, 0);
            s1 = __builtin_amdgcn_mfma_f32_16x16x32_bf16(kf[1][1], qf[s][1], s1, 0, 0, 0);
            // s includes log2(e) (folded into q): p = exp2(s)

            float p0[4], p1[4];
#pragma unroll
            for (int r = 0; r < 4; ++r) {
                p0[r] = fast_exp2(s0[r]);
                p1[r] = fast_exp2(s1[r]);
            }
            lr[s] += (p0[0] + p0[1]) + (p0[2] + p0[3]) + (p1[0] + p1[1]) + (p1[2] + p1[3]);

            union { bf16x8 v8; unsigned d[4]; } P;
            P.d[0] = pack_bf_trunc(p0[0], p0[1]);
            P.d[1] = pack_bf_trunc(p0[2], p0[3]);
            P.d[2] = pack_bf_trunc(p1[0], p1[1]);
            P.d[3] = pack_bf_trunc(p1[2], p1[3]);
#pragma unroll
            for (int c = 0; c < 4; ++c)
                Oc[s][c] = __builtin_amdgcn_mfma_f32_16x16x32_bf16(vf[c], P.v8, Oc[s][c], 0, 0, 0);
        }
    }

    // reduce partial row-sums across the 4 quads (key-slot partials)
#pragma unroll
    for (int s = 0; s < 2; ++s) {
        lr[s] += __shfl_xor(lr[s], 16);
        lr[s] += __shfl_xor(lr[s], 32);
    }

    // combine the two key-halves in LDS (reuse staging memory)
    __syncthreads();
    float* exch = (float*)SL;                 // [128 q][68 pad] f32 = 34816 B
    float* lx   = ((float*)SL) + 128 * 68;    // 128 f32
    if (grp == 1) {
#pragma unroll
        for (int s = 0; s < 2; ++s) {
            const int lq = wq * 32 + 16 * s + l16;
#pragma unroll
            for (int c = 0; c < 4; ++c)
                *(f32x4*)&exch[lq * 68 + 16 * c + 4 * quad] = Oc[s][c];
            if (quad == 0) lx[lq] = lr[s];
        }
    }
    __syncthreads();
    if (grp == 0) {
        const int b = bh >> 2, h = bh & 3;
#pragma unroll
        for (int s = 0; s < 2; ++s) {
            const int lq = wq * 32 + 16 * s + l16;
            const float linv = 1.0f / (lr[s] + lx[lq]);
            ushort* dst = out + (size_t)(b * NSEQ + blockIdx.x * 128 + lq) * HID + h * DHD;
#pragma unroll
            for (int c = 0; c < 4; ++c) {
                const f32x4 o1 = *(const f32x4*)&exch[lq * 68 + 16 * c + 4 * quad];
                u16x4 w;
#pragma unroll
                for (int r = 0; r < 4; ++r) w[r] = f2bf((Oc[s][c][r] + o1[r]) * linv);
                *(u16x4*)(dst + 16 * c + quad * 4) = w;
            }
        }
    }
}

// ---------------------------------------------------------------------------
// Kernel 7: out_proj (bf16 MFMA) + bias + residual + LayerNorm.
// ---------------------------------------------------------------------------
__global__ __launch_bounds__(256) void oproj_ln_mfma(
        const ushort* __restrict__ abuf, const float* __restrict__ Qin,
        const ushort* __restrict__ WoB, const float* __restrict__ bo,
        const float* __restrict__ g, const float* __restrict__ be,
        float* __restrict__ out) {
    __shared__ float yt[32][260];
    const int wv = threadIdx.x >> 6, lane = threadIdx.x & 63;
    const int l16 = lane & 15, quad = lane >> 4;
    const int m0 = blockIdx.x * 32;
    const int n0 = wv * 64;

    f32x4 acc[2][4];
#pragma unroll
    for (int s = 0; s < 2; ++s)
#pragma unroll
        for (int c = 0; c < 4; ++c) acc[s][c] = (f32x4){0.f, 0.f, 0.f, 0.f};

    for (int kk = 0; kk < HID; kk += 32) {
        bf16x8 af[2], bf[4];
#pragma unroll
        for (int s = 0; s < 2; ++s)
            af[s] = *(const bf16x8*)(abuf + (size_t)(m0 + 16 * s + l16) * HID + kk + quad * 8);
#pragma unroll
        for (int c = 0; c < 4; ++c)
            bf[c] = *(const bf16x8*)(WoB + (size_t)(n0 + 16 * c + l16) * HID + kk + quad * 8);
#pragma unroll
        for (int s = 0; s < 2; ++s)
#pragma unroll
            for (int c = 0; c < 4; ++c)
                acc[s][c] = __builtin_amdgcn_mfma_f32_16x16x32_bf16(af[s], bf[c], acc[s][c], 0, 0, 0);
    }

#pragma unroll
    for (int s = 0; s < 2; ++s)
#pragma unroll
        for (int c = 0; c < 4; ++c) {
            const int col = n0 + 16 * c + l16;
            const float bv = bo[col];
#pragma unroll
            for (int r = 0; r < 4; ++r) {
                const int row = 16 * s + quad * 4 + r;
                yt[row][col] = acc[s][c][r] + bv + Qin[(size_t)(m0 + row) * HID + col];
            }
        }
    __syncthreads();

    float gv[4], bev[4];
#pragma unroll
    for (int u = 0; u < 4; ++u) { gv[u] = g[lane + 64 * u]; bev[u] = be[lane + 64 * u]; }

    for (int rr = 0; rr < 8; ++rr) {
        const int row = wv * 8 + rr;
        float sm = 0.f, ssq = 0.f;
        float yv[4];
#pragma unroll
        for (int u = 0; u < 4; ++u) {
            yv[u] = yt[row][lane + 64 * u];
            sm += yv[u]; ssq += yv[u] * yv[u];
        }
#pragma unroll
        for (int off = 32; off >= 1; off >>= 1) {
            sm += __shfl_xor(sm, off);
            ssq += __shfl_xor(ssq, off);
        }
        const float mu = sm * (1.f / 256.f);
        const float rs = rsqrtf(fmaxf(ssq * (1.f / 256.f) - mu * mu, 0.f) + 1e-5f);
        float* dst = out + (size_t)(m0 + row) * HID;
#pragma unroll
        for (int u = 0; u < 4; ++u)
            dst[lane + 64 * u] = (yv[u] - mu) * rs * gv[u] + bev[u];
    }
}

// ---------------------------------------------------------------------------
extern "C" void kernel_launch(void* const* d_in, const int* in_sizes, int n_in,
                              void* d_out, int out_size, void* d_ws, size_t ws_size,
                              hipStream_t stream) {
    const float* inputs       = (const float*)d_in[0];
    const float* Q_in         = (const float*)d_in[1];
    const float* input_coords = (const float*)d_in[2];
    const float* Q_in_coords  = (const float*)d_in[3];
    const float* Wq           = (const float*)d_in[4];
    const float* Wk           = (const float*)d_in[5];
    const float* Wv           = (const float*)d_in[6];
    const float* in_proj_w    = (const float*)d_in[7];
    const float* in_proj_b    = (const float*)d_in[8];
    const float* out_proj_w   = (const float*)d_in[9];
    const float* out_proj_b   = (const float*)d_in[10];
    const float* ln_g         = (const float*)d_in[11];
    const float* ln_b         = (const float*)d_in[12];
    const float* pe_w1        = (const float*)d_in[13];
    const float* pe_b1        = (const float*)d_in[14];
    const float* pe_w2        = (const float*)d_in[15];
    const float* pe_b2        = (const float*)d_in[16];

    char* ws = (char*)d_ws;
    ushort* Wb   = (ushort*)(ws);              // 768*288*2     = 442368
    ushort* WoB  = (ushort*)(ws + 442368);     // 256*256*2     = 131072
    ushort* qp   = (ushort*)(ws + 573440);     // 16384*288*2   = 9437184
    ushort* ip   = (ushort*)(ws + 10010624);   // 9437184
    ushort* qbuf = (ushort*)(ws + 19447808);   // 8388608
    ushort* kbuf = (ushort*)(ws + 27836416);   // 8388608
    ushort* vbuf = (ushort*)(ws + 36225024);   // 8388608 (transposed [bh][64][n])
    ushort* abuf = (ushort*)(ws + 44613632);   // 8388608 -> end 53002240 bytes

    fuse_w_kernel<<<dim3(256, 3), 320, 0, stream>>>(in_proj_w, Wq, Wk, Wv, Wb);
    cast_wo<<<64, 256, 0, stream>>>(out_proj_w, WoB);
    pos_mlp_kernel<<<256, 128, 0, stream>>>(input_coords, Q_in_coords,
                                            pe_w1, pe_b1, pe_w2, pe_b2, ip, qp);
    cast_x_kernel<<<dim3(2048, 2), 256, 0, stream>>>(inputs, Q_in, ip, qp);
    qkv_mfma<<<dim3(128, 12), 256, 0, stream>>>(qp, ip, Wb, in_proj_b,
                                                qbuf, kbuf, vbuf);
    attn_kernel<<<dim3(16, 32), 512, 0, stream>>>(qbuf, kbuf, vbuf, abuf);
    oproj_ln_mfma<<<512, 256, 0, stream>>>(abuf, Q_in, WoB, out_proj_b,
                                           ln_g, ln_b, (float*)d_out);
}

// Round 4
// 207.118 us; speedup vs baseline: 1.2127x; 1.1130x over previous
//
#include <hip/hip_runtime.h>
#include <math.h>

#define HID 256
#define CIN 288      // HID + POS
#define NTOK 16384   // B*N
#define NSEQ 2048
#define NH 4
#define DHD 64
#define TWO_PI 6.2831853071795864769f

typedef __attribute__((ext_vector_type(8))) short bf16x8;
typedef __attribute__((ext_vector_type(4))) float f32x4;
typedef __attribute__((ext_vector_type(4))) unsigned short u16x4;

__device__ __forceinline__ ushort f2bf(float x) {
    unsigned u = __float_as_uint(x);
    u = (u + 0x7FFFu + ((u >> 16) & 1u)) >> 16;
    return (ushort)u;
}

__device__ __forceinline__ float fast_exp2(float x) {
    return __builtin_amdgcn_exp2f(x);   // v_exp_f32
}

// pack two fp32 -> one dword of truncated bf16 (lo=a, hi=b) via v_perm_b32
__device__ __forceinline__ unsigned pack_bf_trunc(float a, float b) {
    return __builtin_amdgcn_perm(__float_as_uint(b), __float_as_uint(a), 0x07060302u);
}

// async global->LDS, 16 B per lane: LDS dst = base + lane*16 (wave-uniform base)
__device__ __forceinline__ void gload_lds16(const ushort* g, ushort* l) {
    __builtin_amdgcn_global_load_lds(
        (const __attribute__((address_space(1))) unsigned*)g,
        (__attribute__((address_space(3))) unsigned*)l, 16, 0, 0);
}

// LDS chunk swizzle for 128B rows (8 x 16B chunks/row): uniform bank classes
__device__ __forceinline__ int sw(int row) {
    return (((row >> 3) << 1) ^ row) & 7;
}

// chunk swizzle for 64B rows (4 x 16B chunks/row)
__device__ __forceinline__ int swv(int row) {
    return ((row & 3) ^ ((row >> 2) & 3));
}

// ---------------------------------------------------------------------------
// Kernel 1 (MERGED PREP): pos_mlp | cast_wo | fuse_w | cast_x in ONE grid.
// The four sub-kernels are mutually independent; the old launch sequence
// serialized them (and pos_mlp alone = 512 waves = 0.5 waves/SIMD -> half the
// chip idle). Dispatch by blockIdx.x range, long-latency low-parallelism
// blocks FIRST so they start early and the 4096 memory-bound cast_x blocks
// fill the machine behind them. All per-thread arithmetic is bit-identical
// to the previous separate kernels.
//   [0,128)      pos_mlp   (256 thr/block, 2x the old 128-thr blocks)
//   [128,192)    cast_wo   (64 blocks)
//   [192,960)    fuse_w    (768 blocks; 256 thr, t<32 also does col 256+t)
//   [960,5056)   cast_x    (4096 blocks)
// ---------------------------------------------------------------------------
__global__ __launch_bounds__(256) void prep_kernel(
        const float* __restrict__ icoords, const float* __restrict__ qcoords,
        const float* __restrict__ w1, const float* __restrict__ b1,
        const float* __restrict__ w2, const float* __restrict__ b2,
        const float* __restrict__ X, const float* __restrict__ Qin,
        const float* __restrict__ inW,
        const float* __restrict__ Wq, const float* __restrict__ Wk,
        const float* __restrict__ Wv,
        const float* __restrict__ Wo,
        ushort* __restrict__ ip, ushort* __restrict__ qp,
        ushort* __restrict__ Wb, ushort* __restrict__ WoB) {
    __shared__ float SMEM[4160];   // pos_mlp: 3072 + 32 + 1024 + 32 = 16640 B
    const int blk = blockIdx.x;
    const int t = threadIdx.x;

    if (blk < 128) {
        // ---------------- pos_mlp ----------------
        float* sw1t = SMEM;            // [96][32] transposed
        float* sb1  = SMEM + 3072;     // [32]
        float* sw2  = SMEM + 3104;     // [32][32]
        float* sb2  = SMEM + 4128;     // [32]
        for (int i = t; i < 96 * 32; i += 256) {
            const int e = i >> 5, r = i & 31;
            sw1t[i] = w1[r * 96 + e];
        }
        for (int i = t; i < 32 * 32; i += 256) sw2[i] = w2[i];
        if (t < 32) { sb1[t] = b1[t]; sb2[t] = b2[t]; }
        __syncthreads();

        const int tok = blk * 256 + t;
        const int which = tok >> 14;
        const int m = tok & (NTOK - 1);
        const float* cr = (which ? qcoords : icoords) + m * 4;
        const float x = cr[1] * TWO_PI;
        const float y = cr[2] * TWO_PI;
        const float z = cr[3] * TWO_PI;

        f32x4 h4[8];
#pragma unroll
        for (int r4 = 0; r4 < 8; ++r4) h4[r4] = *(const f32x4*)&sb1[r4 * 4];

        for (int jj = 0; jj < 16; ++jj) {
            const float inv = 1.0f / (1.0f + 0.0625f * (float)jj);
            const float xs = x * inv, ys = y * inv, zs = z * inv;
            const float cx = __cosf(xs);
            float vals[6];
            int idx[6];
            vals[0] = __sinf(ys);  idx[0] = 2 * jj;
            vals[1] = __cosf(ys);  idx[1] = 2 * jj + 1;
            vals[2] = __sinf(xs);  idx[2] = 32 + 2 * jj;
            vals[3] = cx;          idx[3] = 32 + 2 * jj + 1;
            vals[4] = __sinf(zs);  idx[4] = 64 + 2 * jj;
            vals[5] = cx;          idx[5] = 64 + 2 * jj + 1;   // reference bug: cos of x
#pragma unroll
            for (int u = 0; u < 6; ++u) {
                const float ev = vals[u];
                const f32x4* wr = (const f32x4*)&sw1t[idx[u] * 32];
#pragma unroll
                for (int r4 = 0; r4 < 8; ++r4) h4[r4] += ev * wr[r4];
            }
        }
#pragma unroll
        for (int r4 = 0; r4 < 8; ++r4)
#pragma unroll
            for (int j = 0; j < 4; ++j) h4[r4][j] = fmaxf(h4[r4][j], 0.f);

        ushort* dst = (which ? qp : ip) + (size_t)m * CIN + 256;
#pragma unroll
        for (int c = 0; c < 32; ++c) {
            const f32x4* w4 = (const f32x4*)&sw2[c * 32];
            f32x4 a4 = h4[0] * w4[0];
#pragma unroll
            for (int r4 = 1; r4 < 8; ++r4) a4 += h4[r4] * w4[r4];
            dst[c] = f2bf(sb2[c] + (a4[0] + a4[1]) + (a4[2] + a4[3]));
        }
    } else if (blk < 192) {
        // ---------------- cast_wo ----------------
        const int f = ((blk - 128) * 256 + t) * 4;
        const float4 a = *(const float4*)(Wo + f);
        u16x4 o = {f2bf(a.x), f2bf(a.y), f2bf(a.z), f2bf(a.w)};
        *(u16x4*)(WoB + f) = o;
    } else if (blk < 960) {
        // ---------------- fuse_w ----------------
        __shared__ float wrow[256];
        const int idx = blk - 192;
        const int o = idx & 255;
        const int mat = idx >> 8;
        wrow[t] = inW[(mat * 256 + o) * 256 + t];
        __syncthreads();
        const float* Wm = (mat == 0) ? Wq : ((mat == 1) ? Wk : Wv);
        const int t2 = 256 + (t & 31);
        float acc0 = 0.f, acc1 = 0.f;
#pragma unroll 4
        for (int h = 0; h < 256; ++h) {
            const float wh = wrow[h];
            acc0 += wh * Wm[h * CIN + t];
            acc1 += wh * Wm[h * CIN + t2];
        }
        ushort* dst = Wb + (size_t)(mat * 256 + o) * CIN;
        dst[t] = f2bf(acc0);
        if (t < 32) dst[t2] = f2bf(acc1);
    } else {
        // ---------------- cast_x ----------------
        const int i = blk - 960;
        const int which = i >> 11;
        const size_t f = ((size_t)(i & 2047) * 256 + t) * 8;
        const int row = (int)(f >> 8);
        const int col = (int)(f & 255);
        const float* src = which ? Qin : X;
        ushort* dst = which ? qp : ip;
        const float4 a = *(const float4*)(src + f);
        const float4 b = *(const float4*)(src + f + 4);
        u16x4 o0 = {f2bf(a.x), f2bf(a.y), f2bf(a.z), f2bf(a.w)};
        u16x4 o1 = {f2bf(b.x), f2bf(b.y), f2bf(b.z), f2bf(b.w)};
        *(u16x4*)(dst + (size_t)row * CIN + col) = o0;
        *(u16x4*)(dst + (size_t)row * CIN + col + 4) = o1;
    }
}

// ---------------------------------------------------------------------------
// Kernel 2: QKV projection, bf16 MFMA with LDS-staged A (global_load_lds,
// double-buffered, one barrier per k-step). grid = (128, 12); block = 4 waves.
// ---------------------------------------------------------------------------
__global__ __launch_bounds__(256) void qkv_mfma(
        const ushort* __restrict__ qp, const ushort* __restrict__ ip,
        const ushort* __restrict__ Wb, const float* __restrict__ bias,
        ushort* __restrict__ qout, ushort* __restrict__ kout, ushort* __restrict__ vout) {
    __shared__ ushort SA[2 * 4096];   // 2 x 8 KB
    const int wv = threadIdx.x >> 6, lane = threadIdx.x & 63;
    const int l16 = lane & 15, quad = lane >> 4;
    const int m0b = blockIdx.x * 128;
    const int y = blockIdx.y;
    const int mat = y >> 2;
    const int n0 = y * 64;
    const ushort* A = (mat == 0) ? qp : ip;

    size_t asrc[2];
    int adst[2];
#pragma unroll
    for (int i = 0; i < 2; ++i) {
        const int idx = wv * 128 + i * 64 + lane;
        const int row = idx >> 2, cc = idx & 3;
        asrc[i] = (size_t)(m0b + row) * CIN + cc * 8;
        adst[i] = (wv * 128 + i * 64) * 8;
    }
    int aoff[2];
#pragma unroll
    for (int s = 0; s < 2; ++s)
        aoff[s] = ((32 * wv + 16 * s + l16) * 4 + quad) * 8;

    f32x4 acc[2][4];
#pragma unroll
    for (int s = 0; s < 2; ++s)
#pragma unroll
        for (int c = 0; c < 4; ++c) acc[s][c] = (f32x4){0.f, 0.f, 0.f, 0.f};

#pragma unroll
    for (int i = 0; i < 2; ++i)
        gload_lds16(A + asrc[i], SA + adst[i]);

    for (int t = 0; t < 9; ++t) {
        __syncthreads();
        if (t + 1 < 9) {
            const int bo = ((t + 1) & 1) * 4096;
#pragma unroll
            for (int i = 0; i < 2; ++i)
                gload_lds16(A + asrc[i] + (t + 1) * 32, SA + bo + adst[i]);
        }
        const ushort* buf = SA + (t & 1) * 4096;
        const int kk = t * 32;
        bf16x8 af[2], bf[4];
#pragma unroll
        for (int s = 0; s < 2; ++s)
            af[s] = *(const bf16x8*)(buf + aoff[s]);
#pragma unroll
        for (int c = 0; c < 4; ++c)
            bf[c] = *(const bf16x8*)(Wb + (size_t)(n0 + 16 * c + l16) * CIN + kk + quad * 8);
        if (mat < 2) {
#pragma unroll
            for (int s = 0; s < 2; ++s)
#pragma unroll
                for (int c = 0; c < 4; ++c)
                    acc[s][c] = __builtin_amdgcn_mfma_f32_16x16x32_bf16(bf[c], af[s], acc[s][c], 0, 0, 0);
        } else {
#pragma unroll
            for (int s = 0; s < 2; ++s)
#pragma unroll
                for (int c = 0; c < 4; ++c)
                    acc[s][c] = __builtin_amdgcn_mfma_f32_16x16x32_bf16(af[s], bf[c], acc[s][c], 0, 0, 0);
        }
    }

    const int h = y & 3;
    const int m0 = m0b + wv * 32;
    if (mat < 2) {
        const float scale = (mat == 0) ? (0.125f * 1.44269504088896f) : 1.0f;
        ushort* out = (mat == 0) ? qout : kout;
#pragma unroll
        for (int s = 0; s < 2; ++s) {
            const int tokm = m0 + 16 * s + l16;
            const int b = tokm >> 11, nn = tokm & (NSEQ - 1);
#pragma unroll
            for (int c = 0; c < 4; ++c) {
                const f32x4 b4 = *(const f32x4*)&bias[n0 + 16 * c + quad * 4];
                u16x4 w;
#pragma unroll
                for (int r = 0; r < 4; ++r) w[r] = f2bf((acc[s][c][r] + b4[r]) * scale);
                *(u16x4*)(out + ((size_t)(b * NH + h) * NSEQ + nn) * DHD + 16 * c + quad * 4) = w;
            }
        }
    } else {
#pragma unroll
        for (int s = 0; s < 2; ++s) {
            const int tok0 = m0 + 16 * s + quad * 4;
            const int b = tok0 >> 11, nn0 = tok0 & (NSEQ - 1);
#pragma unroll
            for (int c = 0; c < 4; ++c) {
                const int d = 16 * c + l16;
                const float bv = bias[n0 + d];
                u16x4 w;
#pragma unroll
                for (int r = 0; r < 4; ++r) w[r] = f2bf(acc[s][c][r] + bv);
                *(u16x4*)(vout + ((size_t)(b * NH + h) * DHD + d) * NSEQ + nn0) = w;
            }
        }
    }
}

// ---------------------------------------------------------------------------
// Kernel 3: MFMA flash attention, fixed-max softmax.
// IN-BLOCK SPLIT-K, 8 waves (512 thr): waves 0-3 = keys 0..1023, waves 4-7 =
// keys 1024..2047, SAME 128 queries (32 q/wave -> LDS-read reuse preserved).
// 32-key tiles; per group 3 buffers x (K 4KB + V 4KB) = 24KB; 2 groups = 48KB
// -> 2 blocks/CU. Counted vmcnt pipeline (depth 2). Halves combined in LDS.
// ---------------------------------------------------------------------------
__global__ __launch_bounds__(512, 4) void attn_kernel(
        const ushort* __restrict__ q, const ushort* __restrict__ k,
        const ushort* __restrict__ v, ushort* __restrict__ out) {
    __shared__ ushort SL[24576];   // 48 KB
    const int bh = blockIdx.y;
    const int wv = threadIdx.x >> 6;     // 0..7
    const int grp = wv >> 2;             // key half
    const int wq = wv & 3;               // q sub-block within group
    const int lane = threadIdx.x & 63;
    const int l16 = lane & 15, quad = lane >> 4;
    const int q0 = blockIdx.x * 128 + wq * 32;

    const ushort* qb = q + (size_t)bh * NSEQ * DHD;
    const ushort* kb = k + (size_t)bh * NSEQ * DHD + (size_t)(grp * 1024) * DHD;
    const ushort* vb = v + (size_t)bh * DHD * NSEQ + grp * 1024;
    ushort* SG = SL + grp * 12288;       // per-group staging base (ushorts)

    // Q B-frags for the two 16-query tiles
    bf16x8 qf[2][2];
#pragma unroll
    for (int s = 0; s < 2; ++s)
#pragma unroll
        for (int hh = 0; hh < 2; ++hh)
            qf[s][hh] = *(const bf16x8*)(qb + (size_t)(q0 + 16 * s + l16) * DHD + 32 * hh + quad * 8);

    // staging: per tile, wave wq loads 1 K-chunk-block + 1 V-chunk-block (1KB each)
    // K tile: 32 rows x 128B (8 chunks/row); wave covers rows 8wq..8wq+7
    const int krow_s = 8 * wq + (lane >> 3);
    const int kcg = (lane & 7) ^ sw(krow_s);
    const size_t ksrc = (size_t)krow_s * DHD + kcg * 8;
    const int kdst = wq * 512;           // ushorts; HW adds lane*16B
    // V tile (V^T): 64 rows(d) x 64B (4 chunks/row); wave covers d 16wq..16wq+15
    const int vrow_s = 16 * wq + (lane >> 2);
    const int vcg = (lane & 3) ^ swv(vrow_s);
    const size_t vsrc = (size_t)vrow_s * NSEQ + vcg * 8;
    const int vdst = wq * 512;

    // fragment read offsets (swizzled; ushort units, relative to buffer base)
    const int krow = 8 * (l16 >> 2) + (l16 & 3);   // key-slot permutation
    int koff[2][2];   // [m][hh]
    int voff[4];      // [c]
#pragma unroll
    for (int m = 0; m < 2; ++m) {
        const int row = krow + 4 * m;
#pragma unroll
        for (int hh = 0; hh < 2; ++hh)
            koff[m][hh] = row * 64 + (((hh * 4 + quad) ^ sw(row))) * 8;
    }
#pragma unroll
    for (int c = 0; c < 4; ++c) {
        const int d = 16 * c + l16;
        voff[c] = 2048 + d * 32 + ((quad ^ swv(d))) * 8;
    }

    f32x4 Oc[2][4];
#pragma unroll
    for (int s = 0; s < 2; ++s)
#pragma unroll
        for (int c = 0; c < 4; ++c) Oc[s][c] = (f32x4){0.f, 0.f, 0.f, 0.f};
    float lr[2] = {0.f, 0.f};

    // prologue: prefetch tiles 0,1 (4 loads in flight)
#pragma unroll
    for (int pt = 0; pt < 2; ++pt) {
        ushort* db = SG + pt * 4096;
        gload_lds16(kb + (size_t)(pt * 32) * DHD + ksrc, db + kdst);
        gload_lds16(vb + pt * 32 + vsrc, db + 2048 + vdst);
    }

    int co = 0, po = 8192;   // consumer / prefetch buffer offsets (ushorts)
    for (int t = 0; t < 32; ++t) {
        // retire OWN tile-t loads (leave tile t+1 in flight); barrier => all waves'
        if (t < 31) asm volatile("s_waitcnt vmcnt(2)" ::: "memory");
        else        asm volatile("s_waitcnt vmcnt(0)" ::: "memory");
        __builtin_amdgcn_s_barrier();

        if (t < 30) {   // prefetch tile t+2 into buf freed at t-1
            ushort* db = SG + po;
            gload_lds16(kb + (size_t)((t + 2) * 32) * DHD + ksrc, db + kdst);
            gload_lds16(vb + (t + 2) * 32 + vsrc, db + 2048 + vdst);
            po = (po == 8192) ? 0 : po + 4096;
        }
        const ushort* buf = SG + co;
        co = (co == 8192) ? 0 : co + 4096;

        bf16x8 kf[2][2], vf[4];
#pragma unroll
        for (int m = 0; m < 2; ++m)
#pragma unroll
            for (int hh = 0; hh < 2; ++hh)
                kf[m][hh] = *(const bf16x8*)(buf + koff[m][hh]);
#pragma unroll
        for (int c = 0; c < 4; ++c)
            vf[c] = *(const bf16x8*)(buf + voff[c]);

#pragma unroll
        for (int s = 0; s < 2; ++s) {
            f32x4 s0 = (f32x4){0.f, 0.f, 0.f, 0.f};
            f32x4 s1 = (f32x4){0.f, 0.f, 0.f, 0.f};
            s0 = __builtin_amdgcn_mfma_f32_16x16x32_bf16(kf[0][0], qf[s][0], s0, 0, 0, 0);
            s0 = __builtin_amdgcn_mfma_f32_16x16x32_bf16(kf[0][1], qf[s][1], s0, 0, 0, 0);
            s1 = __builtin_amdgcn_mfma_f32_16x16x32_bf16(kf[1][0], qf[s][0], s1, 0, 0, 0);
            s1 = __builtin_amdgcn_mfma_f32_16x16x32_bf16(kf[1][1], qf[s][1], s1, 0, 0, 0);
            // s includes log2(e) (folded into q): p = exp2(s)

            float p0[4], p1[4];
#pragma unroll
            for (int r = 0; r < 4; ++r) {
                p0[r] = fast_exp2(s0[r]);
                p1[r] = fast_exp2(s1[r]);
            }
            lr[s] += (p0[0] + p0[1]) + (p0[2] + p0[3]) + (p1[0] + p1[1]) + (p1[2] + p1[3]);

            union { bf16x8 v8; unsigned d[4]; } P;
            P.d[0] = pack_bf_trunc(p0[0], p0[1]);
            P.d[1] = pack_bf_trunc(p0[2], p0[3]);
            P.d[2] = pack_bf_trunc(p1[0], p1[1]);
            P.d[3] = pack_bf_trunc(p1[2], p1[3]);
#pragma unroll
            for (int c = 0; c < 4; ++c)
                Oc[s][c] = __builtin_amdgcn_mfma_f32_16x16x32_bf16(vf[c], P.v8, Oc[s][c], 0, 0, 0);
        }
    }

    // reduce partial row-sums across the 4 quads (key-slot partials)
#pragma unroll
    for (int s = 0; s < 2; ++s) {
        lr[s] += __shfl_xor(lr[s], 16);
        lr[s] += __shfl_xor(lr[s], 32);
    }

    // combine the two key-halves in LDS (reuse staging memory)
    __syncthreads();
    float* exch = (float*)SL;                 // [128 q][68 pad] f32 = 34816 B
    float* lx   = ((float*)SL) + 128 * 68;    // 128 f32
    if (grp == 1) {
#pragma unroll
        for (int s = 0; s < 2; ++s) {
            const int lq = wq * 32 + 16 * s + l16;
#pragma unroll
            for (int c = 0; c < 4; ++c)
                *(f32x4*)&exch[lq * 68 + 16 * c + 4 * quad] = Oc[s][c];
            if (quad == 0) lx[lq] = lr[s];
        }
    }
    __syncthreads();
    if (grp == 0) {
        const int b = bh >> 2, h = bh & 3;
#pragma unroll
        for (int s = 0; s < 2; ++s) {
            const int lq = wq * 32 + 16 * s + l16;
            const float linv = 1.0f / (lr[s] + lx[lq]);
            ushort* dst = out + (size_t)(b * NSEQ + blockIdx.x * 128 + lq) * HID + h * DHD;
#pragma unroll
            for (int c = 0; c < 4; ++c) {
                const f32x4 o1 = *(const f32x4*)&exch[lq * 68 + 16 * c + 4 * quad];
                u16x4 w;
#pragma unroll
                for (int r = 0; r < 4; ++r) w[r] = f2bf((Oc[s][c][r] + o1[r]) * linv);
                *(u16x4*)(dst + 16 * c + quad * 4) = w;
            }
        }
    }
}

// ---------------------------------------------------------------------------
// Kernel 4: out_proj (bf16 MFMA) + bias + residual + LayerNorm.
// ---------------------------------------------------------------------------
__global__ __launch_bounds__(256) void oproj_ln_mfma(
        const ushort* __restrict__ abuf, const float* __restrict__ Qin,
        const ushort* __restrict__ WoB, const float* __restrict__ bo,
        const float* __restrict__ g, const float* __restrict__ be,
        float* __restrict__ out) {
    __shared__ float yt[32][260];
    const int wv = threadIdx.x >> 6, lane = threadIdx.x & 63;
    const int l16 = lane & 15, quad = lane >> 4;
    const int m0 = blockIdx.x * 32;
    const int n0 = wv * 64;

    f32x4 acc[2][4];
#pragma unroll
    for (int s = 0; s < 2; ++s)
#pragma unroll
        for (int c = 0; c < 4; ++c) acc[s][c] = (f32x4){0.f, 0.f, 0.f, 0.f};

    for (int kk = 0; kk < HID; kk += 32) {
        bf16x8 af[2], bf[4];
#pragma unroll
        for (int s = 0; s < 2; ++s)
            af[s] = *(const bf16x8*)(abuf + (size_t)(m0 + 16 * s + l16) * HID + kk + quad * 8);
#pragma unroll
        for (int c = 0; c < 4; ++c)
            bf[c] = *(const bf16x8*)(WoB + (size_t)(n0 + 16 * c + l16) * HID + kk + quad * 8);
#pragma unroll
        for (int s = 0; s < 2; ++s)
#pragma unroll
            for (int c = 0; c < 4; ++c)
                acc[s][c] = __builtin_amdgcn_mfma_f32_16x16x32_bf16(af[s], bf[c], acc[s][c], 0, 0, 0);
    }

#pragma unroll
    for (int s = 0; s < 2; ++s)
#pragma unroll
        for (int c = 0; c < 4; ++c) {
            const int col = n0 + 16 * c + l16;
            const float bv = bo[col];
#pragma unroll
            for (int r = 0; r < 4; ++r) {
                const int row = 16 * s + quad * 4 + r;
                yt[row][col] = acc[s][c][r] + bv + Qin[(size_t)(m0 + row) * HID + col];
            }
        }
    __syncthreads();

    float gv[4], bev[4];
#pragma unroll
    for (int u = 0; u < 4; ++u) { gv[u] = g[lane + 64 * u]; bev[u] = be[lane + 64 * u]; }

    for (int rr = 0; rr < 8; ++rr) {
        const int row = wv * 8 + rr;
        float sm = 0.f, ssq = 0.f;
        float yv[4];
#pragma unroll
        for (int u = 0; u < 4; ++u) {
            yv[u] = yt[row][lane + 64 * u];
            sm += yv[u]; ssq += yv[u] * yv[u];
        }
#pragma unroll
        for (int off = 32; off >= 1; off >>= 1) {
            sm += __shfl_xor(sm, off);
            ssq += __shfl_xor(ssq, off);
        }
        const float mu = sm * (1.f / 256.f);
        const float rs = rsqrtf(fmaxf(ssq * (1.f / 256.f) - mu * mu, 0.f) + 1e-5f);
        float* dst = out + (size_t)(m0 + row) * HID;
#pragma unroll
        for (int u = 0; u < 4; ++u)
            dst[lane + 64 * u] = (yv[u] - mu) * rs * gv[u] + bev[u];
    }
}

// ---------------------------------------------------------------------------
extern "C" void kernel_launch(void* const* d_in, const int* in_sizes, int n_in,
                              void* d_out, int out_size, void* d_ws, size_t ws_size,
                              hipStream_t stream) {
    const float* inputs       = (const float*)d_in[0];
    const float* Q_in         = (const float*)d_in[1];
    const float* input_coords = (const float*)d_in[2];
    const float* Q_in_coords  = (const float*)d_in[3];
    const float* Wq           = (const float*)d_in[4];
    const float* Wk           = (const float*)d_in[5];
    const float* Wv           = (const float*)d_in[6];
    const float* in_proj_w    = (const float*)d_in[7];
    const float* in_proj_b    = (const float*)d_in[8];
    const float* out_proj_w   = (const float*)d_in[9];
    const float* out_proj_b   = (const float*)d_in[10];
    const float* ln_g         = (const float*)d_in[11];
    const float* ln_b         = (const float*)d_in[12];
    const float* pe_w1        = (const float*)d_in[13];
    const float* pe_b1        = (const float*)d_in[14];
    const float* pe_w2        = (const float*)d_in[15];
    const float* pe_b2        = (const float*)d_in[16];

    char* ws = (char*)d_ws;
    ushort* Wb   = (ushort*)(ws);              // 768*288*2     = 442368
    ushort* WoB  = (ushort*)(ws + 442368);     // 256*256*2     = 131072
    ushort* qp   = (ushort*)(ws + 573440);     // 16384*288*2   = 9437184
    ushort* ip   = (ushort*)(ws + 10010624);   // 9437184
    ushort* qbuf = (ushort*)(ws + 19447808);   // 8388608
    ushort* kbuf = (ushort*)(ws + 27836416);   // 8388608
    ushort* vbuf = (ushort*)(ws + 36225024);   // 8388608 (transposed [bh][64][n])
    ushort* abuf = (ushort*)(ws + 44613632);   // 8388608 -> end 53002240 bytes

    prep_kernel<<<5056, 256, 0, stream>>>(input_coords, Q_in_coords,
                                          pe_w1, pe_b1, pe_w2, pe_b2,
                                          inputs, Q_in, in_proj_w,
                                          Wq, Wk, Wv, out_proj_w,
                                          ip, qp, Wb, WoB);
    qkv_mfma<<<dim3(128, 12), 256, 0, stream>>>(qp, ip, Wb, in_proj_b,
                                                qbuf, kbuf, vbuf);
    attn_kernel<<<dim3(16, 32), 512, 0, stream>>>(qbuf, kbuf, vbuf, abuf);
    oproj_ln_mfma<<<512, 256, 0, stream>>>(abuf, Q_in, WoB, out_proj_b,
                                           ln_g, ln_b, (float*)d_out);
}